// Round 5
// baseline (280.154 us; speedup 1.0000x reference)
//
#include <hip/hip_runtime.h>
#include <stdint.h>

#define L_NR 192
#define S_NS 256
#define D_   256
#define H_   8
#define C_   32

typedef __bf16    bf16x8_t __attribute__((ext_vector_type(8)));
typedef _Float16  half4_t  __attribute__((ext_vector_type(4)));
typedef float     f32x4_t  __attribute__((ext_vector_type(4)));

__device__ __forceinline__ float bflo(unsigned int u) { return __uint_as_float(u << 16); }
__device__ __forceinline__ unsigned int f2b(float f) {
    unsigned int x = __float_as_uint(f);
    return (x + 0x7fffu + ((x >> 16) & 1u)) >> 16;   // RNE
}
__device__ __forceinline__ unsigned short f2h(float f) {
    union { _Float16 h; unsigned short u; } cv; cv.h = (_Float16)f; return cv.u;
}

// ---- Convert 5 fp32 weight matrices (256x256) to bf16 in workspace ----
__global__ __launch_bounds__(256) void convw_kernel(
    const float* __restrict__ wq, const float* __restrict__ wk,
    const float* __restrict__ wv, const float* __restrict__ wg,
    const float* __restrict__ wo, unsigned short* __restrict__ dst)
{
    int mat = blockIdx.y;
    const float* src = (mat == 0) ? wq : (mat == 1) ? wk : (mat == 2) ? wv
                     : (mat == 3) ? wg : wo;
    int i = (blockIdx.x * 256 + threadIdx.x) * 4;
    float4 v = *(const float4*)(src + i);
    uint2 w;
    w.x = f2b(v.x) | (f2b(v.y) << 16);
    w.y = f2b(v.z) | (f2b(v.w) << 16);
    *(uint2*)(dst + (size_t)mat * 65536 + i) = w;
}

// ---------------- LayerNorm: m fp32 (S,L,D) -> xn bf16 (L,S,D) ----------------
__global__ __launch_bounds__(256) void ln_kernel(
    const float* __restrict__ m,
    const float* __restrict__ lns,
    const float* __restrict__ lnb,
    unsigned short* __restrict__ xn)
{
    int tid = threadIdx.x;
    int lane = tid & 63, wave = tid >> 6;
    int r = blockIdx.x * 4 + wave;          // r = s*L + l
    int s = r / L_NR, l = r % L_NR;

    float4 x = ((const float4*)(m + (size_t)r * D_))[lane];

    float sum = x.x + x.y + x.z + x.w;
    float ss  = x.x*x.x + x.y*x.y + x.z*x.z + x.w*x.w;
#pragma unroll
    for (int off = 32; off > 0; off >>= 1) {
        sum += __shfl_xor(sum, off, 64);
        ss  += __shfl_xor(ss,  off, 64);
    }
    float mean = sum * (1.0f/256.0f);
    float var  = ss  * (1.0f/256.0f) - mean * mean;
    float rstd = rsqrtf(fmaxf(var, 0.0f) + 1e-5f);

    float4 sc = ((const float4*)lns)[lane];
    float4 bi = ((const float4*)lnb)[lane];

    float y0 = (x.x - mean) * rstd * sc.x + bi.x;
    float y1 = (x.y - mean) * rstd * sc.y + bi.y;
    float y2 = (x.z - mean) * rstd * sc.z + bi.z;
    float y3 = (x.w - mean) * rstd * sc.w + bi.w;

    uint2 w;
    w.x = f2b(y0) | (f2b(y1) << 16);
    w.y = f2b(y2) | (f2b(y3) << 16);
    *(uint2*)(xn + ((size_t)l * S_NS + s) * D_ + lane * 4) = w;
}

// ------------- Projections (LDS-B, conflict-free swizzle): xn @ W^T -------------
// Round-5:
//  * __launch_bounds__(256,4): budget 128 = 64 arch + 64 accum. acc[4][4]=64
//    accum exactly; arch need ~60 after dropping depth-2 prefetch (a2 was 16
//    VGPRs for zero measured gain in round 4). -> 4 blocks/CU (was 2-3).
//  * keep XCD regroup (round 4: FETCH 49->15 MB, keeps A in-XCD L2).
//  Spill tripwire: FETCH_SIZE must stay ~15 MB.
#define TP 72

__global__ __launch_bounds__(256, 4) void proj_kernel(
    const unsigned short* __restrict__ xn,
    const unsigned short* __restrict__ wbf,   // 4 matrices, bf16, 65536 each
    const float* __restrict__ bg,
    unsigned short* __restrict__ qb, unsigned short* __restrict__ kb,
    unsigned short* __restrict__ vb, unsigned short* __restrict__ gb)
{
    __shared__ __align__(16) unsigned short Sl[S_NS * TP];   // 36864 B (B-stage: first 32 KB)

    int tid  = threadIdx.x;
    int lane = tid & 63, wave = tid >> 6;
    int quad = lane >> 4, l16 = lane & 15;

    // --- XCD regroup: invert hw = l%8 + 8*((l/8)*16 + y) ---
    int hw   = blockIdx.y * 192 + blockIdx.x;   // dispatch index (x-fastest)
    int xcd  = hw & 7;
    int slot = hw >> 3;
    int y    = slot & 15;
    int l    = (slot >> 4) * 8 + xcd;

    int mat = y >> 2;
    int n0  = (y & 3) * 64;
    const unsigned short* W = wbf + (size_t)mat * 65536 + (size_t)n0 * 256;

    // stage B chunk (64 n x 256 k): coalesced global, swizzled LDS
#pragma unroll
    for (int j = 0; j < 8; ++j) {
        int c  = j * 256 + tid;
        int n  = c >> 5, kk = c & 31;
        int ks = kk >> 2, kq = kk & 3;
        int sw = (n & 15) ^ kq ^ ((ks & 1) << 2);
        uint4 d = *(const uint4*)(W + n * 256 + kk * 8);
        *(uint4*)&Sl[ks * 2048 + (n >> 4) * 512 + kq * 128 + sw * 8] = d;
    }
    __syncthreads();

    int row0 = l * 256 + wave * 64;
    const unsigned short* arow = xn + (size_t)(row0 + l16) * D_ + quad * 8;

    f32x4_t acc[4][4];
#pragma unroll
    for (int mt = 0; mt < 4; ++mt)
#pragma unroll
        for (int nt = 0; nt < 4; ++nt) acc[mt][nt] = (f32x4_t){0.f,0.f,0.f,0.f};

    bf16x8_t a_cur[4], a_nxt[4];
#pragma unroll
    for (int mt = 0; mt < 4; ++mt) a_cur[mt] = *(const bf16x8_t*)(arow + mt * 16 * D_);

    int swb = l16 ^ quad;
#pragma unroll
    for (int ks = 0; ks < 8; ++ks) {
        if (ks < 7) {
#pragma unroll
            for (int mt = 0; mt < 4; ++mt)
                a_nxt[mt] = *(const bf16x8_t*)(arow + mt * 16 * D_ + (ks + 1) * 32);
        }
        int kbase = ks * 2048 + quad * 128 + (swb ^ ((ks & 1) << 2)) * 8;
#pragma unroll
        for (int nt = 0; nt < 4; ++nt) {
            bf16x8_t bfr = *(const bf16x8_t*)&Sl[kbase + nt * 512];
#pragma unroll
            for (int mt = 0; mt < 4; ++mt)
                acc[mt][nt] = __builtin_amdgcn_mfma_f32_16x16x32_bf16(a_cur[mt], bfr, acc[mt][nt], 0, 0, 0);
        }
#pragma unroll
        for (int mt = 0; mt < 4; ++mt) a_cur[mt] = a_nxt[mt];
    }
    __syncthreads();   // B-stage dead; Sl becomes the transpose tile

    const float qscale = 0.17677669529663687f;  // 1/sqrt(32)
#pragma unroll
    for (int nt = 0; nt < 4; ++nt) {
        int n = n0 + nt * 16 + l16;
        float bgn = bg[n];
#pragma unroll
        for (int mt = 0; mt < 4; ++mt) {
#pragma unroll
            for (int r = 0; r < 4; ++r) {
                int srow = wave * 64 + mt * 16 + quad * 4 + r;
                float v = acc[mt][nt][r];
                unsigned short o;
                if (mat == 0)      o = (unsigned short)f2b(v * qscale);
                else if (mat == 1) o = (unsigned short)f2b(v);
                else if (mat == 2) o = f2h(v);                       // v as f16
                else               o = (unsigned short)f2b(1.0f / (1.0f + __expf(-(v + bgn))));
                Sl[srow * TP + nt * 16 + l16] = o;
            }
        }
    }
    __syncthreads();

    // coalesced store: chunk = heads h0,h0+1 contiguous (each 8192 elems)
    unsigned short* dstb = (mat == 0) ? qb : (mat == 1) ? kb : (mat == 2) ? vb : gb;
    size_t cbase = ((size_t)l * H_ + (n0 >> 5)) * 8192;
#pragma unroll
    for (int j = 0; j < 8; ++j) {
        int idx = j * 2048 + tid * 8;       // 16384 elems total
        int s = idx >> 6, c8 = idx & 63;
        uint4 d = *(const uint4*)&Sl[s * TP + c8];
        *(uint4*)(dstb + cbase + (size_t)(c8 >> 5) * 8192 + s * 32 + (c8 & 31)) = d;
    }
}

// ------------- MFMA attention per (l,h) -------------
// Round-3: online softmax + __launch_bounds__(256,3): no spills.
#define KP 40    // K LDS row stride (bf16 elems)
#define VP 264   // V^T LDS row stride (f16 elems)
#define VXOR(c) (((((c) >> 3) & 3)) << 4)   // bank-spread swizzle for V^T staging

__global__ __launch_bounds__(256, 3) void attn_kernel(
    const unsigned short* __restrict__ qb, const unsigned short* __restrict__ kb,
    const unsigned short* __restrict__ vb, const unsigned short* __restrict__ gb,
    const int* __restrict__ seq_pad, const int* __restrict__ res_pad,
    unsigned short* __restrict__ ctxg)
{
    __shared__ __align__(16) unsigned short Klds[S_NS * KP];
    __shared__ __align__(16) unsigned short Vlds[C_ * VP];
    __shared__ unsigned int padm[16];

    int tid  = threadIdx.x;
    int lane = tid & 63, wave = tid >> 6;
    int quad = lane >> 4, l16 = lane & 15;
    int lh = blockIdx.x, l = lh >> 3, h = lh & 7;
    size_t base = (size_t)lh * (S_NS * C_);

    const uint4* ksrc = (const uint4*)(kb + base);
#pragma unroll
    for (int i = 0; i < 4; ++i) {
        int idx = i * 256 + tid;
        int s = idx >> 2, c8 = (idx & 3) * 8;
        *(uint4*)(Klds + s * KP + c8) = ksrc[idx];
    }
    // stage V (row-major f16 (S,C)) -> transposed V^T LDS [c][s], swizzled
    const uint4* vsrc = (const uint4*)(vb + base);
#pragma unroll
    for (int i = 0; i < 4; ++i) {
        int idx = i * 256 + tid;
        int s = idx >> 2, c8 = (idx & 3) * 8;
        uint4 d = vsrc[idx];
        const unsigned short* p = (const unsigned short*)&d;
#pragma unroll
        for (int k = 0; k < 8; ++k) {
            int c = c8 + k;
            Vlds[c * VP + (s ^ VXOR(c))] = p[k];
        }
    }
    if (tid < 16) {
        unsigned int pm = 0;
        for (int mt = 0; mt < 16; ++mt)
            pm |= (seq_pad[mt * 16 + tid] != 0 ? 1u : 0u) << mt;
        padm[tid] = pm;
    }
    __syncthreads();

    // pad flag computed redundantly per-thread (no 2nd barrier)
    unsigned int allm = 0xFFFFu;
#pragma unroll
    for (int i = 0; i < 16; ++i) allm &= padm[i];
    int flagall = (res_pad[l] != 0) || (allm == 0xFFFFu);

    unsigned int keep[4];
#pragma unroll
    for (int r = 0; r < 4; ++r)
        keep[r] = flagall ? 0xFFFFu : (~padm[quad * 4 + r] & 0xFFFFu);

    const float LOG2E = 1.4426950408889634f;
    int vx0 = VXOR(l16), vx1 = VXOR(16 + l16);

    for (int qt = 0; qt < 4; ++qt) {
        int sb = wave * 64 + qt * 16;

        // prefetch gate values for the epilogue (latency hides under QK+softmax)
        unsigned short gr0[4], gr1[4];
#pragma unroll
        for (int r = 0; r < 4; ++r) {
            int s = sb + quad * 4 + r;
            gr0[r] = gb[base + (size_t)s * C_ + l16];
            gr1[r] = gb[base + (size_t)s * C_ + 16 + l16];
        }

        bf16x8_t qf = *(const bf16x8_t*)(qb + base + (size_t)(sb + l16) * C_ + quad * 8);

        float mk = -3.0e38f;                 // running max, log2 domain
        float sp = 0.0f;                     // per-lane partial sum (current mk frame)
        f32x4_t c0 = (f32x4_t){0.f,0.f,0.f,0.f}, c1 = (f32x4_t){0.f,0.f,0.f,0.f};

#pragma unroll
        for (int g = 0; g < 2; ++g) {
            // ---- QK^T for 8 key tiles (128 keys) ----
            f32x4_t a[8];
#pragma unroll
            for (int j = 0; j < 8; ++j) {
                int kt = g * 8 + j;
                bf16x8_t kf = *(const bf16x8_t*)(Klds + (kt * 16 + l16) * KP + quad * 8);
                a[j] = __builtin_amdgcn_mfma_f32_16x16x32_bf16(kf, qf, (f32x4_t){0.f,0.f,0.f,0.f}, 0, 0, 0);
            }
            // ---- group max (tree) + cross-quad reduce ----
            float p0 = fmaxf(fmaxf(a[0][0], a[0][1]), fmaxf(a[0][2], a[0][3]));
            float p1 = fmaxf(fmaxf(a[1][0], a[1][1]), fmaxf(a[1][2], a[1][3]));
            float p2 = fmaxf(fmaxf(a[2][0], a[2][1]), fmaxf(a[2][2], a[2][3]));
            float p3 = fmaxf(fmaxf(a[3][0], a[3][1]), fmaxf(a[3][2], a[3][3]));
            float p4 = fmaxf(fmaxf(a[4][0], a[4][1]), fmaxf(a[4][2], a[4][3]));
            float p5 = fmaxf(fmaxf(a[5][0], a[5][1]), fmaxf(a[5][2], a[5][3]));
            float p6 = fmaxf(fmaxf(a[6][0], a[6][1]), fmaxf(a[6][2], a[6][3]));
            float p7 = fmaxf(fmaxf(a[7][0], a[7][1]), fmaxf(a[7][2], a[7][3]));
            float gm = fmaxf(fmaxf(fmaxf(p0, p1), fmaxf(p2, p3)),
                             fmaxf(fmaxf(p4, p5), fmaxf(p6, p7)));
            gm = fmaxf(gm, __shfl_xor(gm, 16, 64));
            gm = fmaxf(gm, __shfl_xor(gm, 32, 64));
            float gmk = gm * LOG2E;

            // ---- defer-rescale: only if group max exceeds running max + 11 (log2) ----
            bool need = gmk > mk + 11.0f;
            if (__any(need)) {
                float nmk = fmaxf(mk, gmk);
                float f = __builtin_amdgcn_exp2f(mk - nmk);   // 0 on first group (c,sp are 0)
                mk = nmk;
                sp *= f;
#pragma unroll
                for (int r = 0; r < 4; ++r) {
                    float fr = __shfl(f, (lane & 48) | (quad * 4 + r), 64);
                    c0[r] *= fr; c1[r] *= fr;
                }
            }

            // ---- exp + mask + f16 convert fused; per-lane partial sums ----
            half4_t pf[8];
            float s0 = 0.f, s1 = 0.f, s2 = 0.f, s3 = 0.f;
#pragma unroll
            for (int j = 0; j < 8; ++j) {
                int kt = g * 8 + j;
                float e0 = __builtin_amdgcn_exp2f(a[j][0] * LOG2E - mk);
                float e1 = __builtin_amdgcn_exp2f(a[j][1] * LOG2E - mk);
                float e2 = __builtin_amdgcn_exp2f(a[j][2] * LOG2E - mk);
                float e3 = __builtin_amdgcn_exp2f(a[j][3] * LOG2E - mk);
                e0 = ((keep[0] >> kt) & 1u) ? e0 : 0.0f;
                e1 = ((keep[1] >> kt) & 1u) ? e1 : 0.0f;
                e2 = ((keep[2] >> kt) & 1u) ? e2 : 0.0f;
                e3 = ((keep[3] >> kt) & 1u) ? e3 : 0.0f;
                s0 += e0; s1 += e1; s2 += e2; s3 += e3;
                half4_t t;
                t[0] = (_Float16)e0; t[1] = (_Float16)e1;
                t[2] = (_Float16)e2; t[3] = (_Float16)e3;
                pf[j] = t;
            }
            sp += (s0 + s1) + (s2 + s3);

            // ---- PV for the group's 8 tiles ----
#pragma unroll
            for (int j = 0; j < 8; ++j) {
                int kt = g * 8 + j;
                int toff = kt * 16 + quad * 4;
                half4_t v0 = *(const half4_t*)(Vlds + l16 * VP        + (toff ^ vx0));
                half4_t v1 = *(const half4_t*)(Vlds + (16 + l16) * VP + (toff ^ vx1));
                c0 = __builtin_amdgcn_mfma_f32_16x16x16f16(pf[j], v0, c0, 0, 0, 0);
                c1 = __builtin_amdgcn_mfma_f32_16x16x16f16(pf[j], v1, c1, 0, 0, 0);
            }
        }

        // ---- final sum reduce + normalize + gate + store ----
        sp += __shfl_xor(sp, 16, 64);
        sp += __shfl_xor(sp, 32, 64);
        float inv = 1.0f / sp;               // rcp hides under the epilogue shfls

#pragma unroll
        for (int r = 0; r < 4; ++r) {
            int s = sb + quad * 4 + r;
            float iv = __shfl(inv, (lane & 48) | (quad * 4 + r), 64);
            float g0 = bflo((unsigned int)gr0[r]);
            float g1 = bflo((unsigned int)gr1[r]);
            unsigned short* op = ctxg + (size_t)(l * S_NS + s) * D_ + h * C_;
            op[l16]      = (unsigned short)f2b(c0[r] * iv * g0);
            op[16 + l16] = (unsigned short)f2b(c1[r] * iv * g1);
        }
    }
}

// ------------- Output projection (LDS-B): ctxg @ wo^T + bo -> out fp32 (S,L,D) -------------
// Round-5: same as proj: (256,4) + depth-1 prefetch + XCD regroup.
__global__ __launch_bounds__(256, 4) void out_kernel(
    const unsigned short* __restrict__ ctxg,
    const unsigned short* __restrict__ wob,   // bf16 wo
    const float* __restrict__ bo,
    float* __restrict__ out)
{
    __shared__ __align__(16) unsigned short Bl[16384];   // 32 KB

    int tid  = threadIdx.x;
    int lane = tid & 63, wave = tid >> 6;
    int quad = lane >> 4, l16 = lane & 15;

    // --- XCD regroup: invert hw = l%8 + 8*((l/8)*4 + y) ---
    int hw   = blockIdx.y * 192 + blockIdx.x;   // dispatch index (x-fastest)
    int xcd  = hw & 7;
    int slot = hw >> 3;
    int y    = slot & 3;
    int l    = (slot >> 2) * 8 + xcd;

    int n0   = y * 64;
    const unsigned short* W = wob + (size_t)n0 * 256;

#pragma unroll
    for (int j = 0; j < 8; ++j) {
        int c  = j * 256 + tid;
        int n  = c >> 5, kk = c & 31;
        int ks = kk >> 2, kq = kk & 3;
        int sw = (n & 15) ^ kq ^ ((ks & 1) << 2);
        uint4 d = *(const uint4*)(W + n * 256 + kk * 8);
        *(uint4*)&Bl[ks * 2048 + (n >> 4) * 512 + kq * 128 + sw * 8] = d;
    }
    __syncthreads();

    int row0 = l * 256 + wave * 64;
    const unsigned short* arow = ctxg + (size_t)(row0 + l16) * D_ + quad * 8;

    f32x4_t acc[4][4];
#pragma unroll
    for (int mt = 0; mt < 4; ++mt)
#pragma unroll
        for (int nt = 0; nt < 4; ++nt) acc[mt][nt] = (f32x4_t){0.f,0.f,0.f,0.f};

    bf16x8_t a_cur[4], a_nxt[4];
#pragma unroll
    for (int mt = 0; mt < 4; ++mt) a_cur[mt] = *(const bf16x8_t*)(arow + mt * 16 * D_);

    int swb = l16 ^ quad;
#pragma unroll
    for (int ks = 0; ks < 8; ++ks) {
        if (ks < 7) {
#pragma unroll
            for (int mt = 0; mt < 4; ++mt)
                a_nxt[mt] = *(const bf16x8_t*)(arow + mt * 16 * D_ + (ks + 1) * 32);
        }
        int kbase = ks * 2048 + quad * 128 + (swb ^ ((ks & 1) << 2)) * 8;
#pragma unroll
        for (int nt = 0; nt < 4; ++nt) {
            bf16x8_t bfr = *(const bf16x8_t*)&Bl[kbase + nt * 512];
#pragma unroll
            for (int mt = 0; mt < 4; ++mt)
                acc[mt][nt] = __builtin_amdgcn_mfma_f32_16x16x32_bf16(a_cur[mt], bfr, acc[mt][nt], 0, 0, 0);
        }
#pragma unroll
        for (int mt = 0; mt < 4; ++mt) a_cur[mt] = a_nxt[mt];
    }

#pragma unroll
    for (int nt = 0; nt < 4; ++nt) {
        int n = n0 + nt * 16 + l16;
        float bias = bo[n];
#pragma unroll
        for (int mt = 0; mt < 4; ++mt) {
#pragma unroll
            for (int r = 0; r < 4; ++r) {
                int s = wave * 64 + mt * 16 + quad * 4 + r;
                out[((size_t)s * L_NR + l) * D_ + n] = acc[mt][nt][r] + bias;
            }
        }
    }
}

extern "C" void kernel_launch(void* const* d_in, const int* in_sizes, int n_in,
                              void* d_out, int out_size, void* d_ws, size_t ws_size,
                              hipStream_t stream) {
    const float* m     = (const float*)d_in[0];
    const int* seq_pad = (const int*)d_in[1];
    const int* res_pad = (const int*)d_in[2];
    const float* lns   = (const float*)d_in[3];
    const float* lnb   = (const float*)d_in[4];
    const float* wq    = (const float*)d_in[5];
    const float* wk    = (const float*)d_in[6];
    const float* wv    = (const float*)d_in[7];
    const float* wg    = (const float*)d_in[8];
    const float* bg    = (const float*)d_in[9];
    const float* wo    = (const float*)d_in[10];
    const float* bo    = (const float*)d_in[11];
    float* out         = (float*)d_out;

    const size_t NE = (size_t)L_NR * S_NS * D_;   // 12,582,912 elements
    unsigned short* xn = (unsigned short*)d_ws;   // bf16 (L,S,D); reused as ctxg
    unsigned short* qb = xn + NE;
    unsigned short* kb = qb + NE;
    unsigned short* vb = kb + NE;                 // f16 (L,H,S,C) row-major
    unsigned short* gb = vb + NE;
    unsigned short* wbf = gb + NE;                // 5 x 65536 bf16 weights
    unsigned short* ctxg = xn;                    // attn no longer needs xn

    convw_kernel<<<dim3(64, 5), 256, 0, stream>>>(wq, wk, wv, wg, wo, wbf);
    ln_kernel<<<12288, 256, 0, stream>>>(m, lns, lnb, xn);
    proj_kernel<<<dim3(192, 16), 256, 0, stream>>>(xn, wbf, bg, qb, kb, vb, gb);
    attn_kernel<<<L_NR * H_, 256, 0, stream>>>(qb, kb, vb, gb, seq_pad, res_pad, ctxg);
    out_kernel<<<dim3(192, 4), 256, 0, stream>>>(ctxg, wbf + 4 * 65536, bo, out);
}

// Round 6
// 259.829 us; speedup vs baseline: 1.0782x; 1.0782x over previous
//
#include <hip/hip_runtime.h>
#include <stdint.h>

#define L_NR 192
#define S_NS 256
#define D_   256
#define H_   8
#define C_   32

typedef __bf16    bf16x8_t __attribute__((ext_vector_type(8)));
typedef _Float16  half4_t  __attribute__((ext_vector_type(4)));
typedef float     f32x4_t  __attribute__((ext_vector_type(4)));

__device__ __forceinline__ float bflo(unsigned int u) { return __uint_as_float(u << 16); }
__device__ __forceinline__ unsigned int f2b(float f) {
    unsigned int x = __float_as_uint(f);
    return (x + 0x7fffu + ((x >> 16) & 1u)) >> 16;   // RNE
}
__device__ __forceinline__ unsigned short f2h(float f) {
    union { _Float16 h; unsigned short u; } cv; cv.h = (_Float16)f; return cv.u;
}

// ---- Convert 5 fp32 weight matrices (256x256) to bf16 in workspace ----
__global__ __launch_bounds__(256) void convw_kernel(
    const float* __restrict__ wq, const float* __restrict__ wk,
    const float* __restrict__ wv, const float* __restrict__ wg,
    const float* __restrict__ wo, unsigned short* __restrict__ dst)
{
    int mat = blockIdx.y;
    const float* src = (mat == 0) ? wq : (mat == 1) ? wk : (mat == 2) ? wv
                     : (mat == 3) ? wg : wo;
    int i = (blockIdx.x * 256 + threadIdx.x) * 4;
    float4 v = *(const float4*)(src + i);
    uint2 w;
    w.x = f2b(v.x) | (f2b(v.y) << 16);
    w.y = f2b(v.z) | (f2b(v.w) << 16);
    *(uint2*)(dst + (size_t)mat * 65536 + i) = w;
}

// ---------------- LayerNorm: m fp32 (S,L,D) -> xn bf16 (L,S,D) ----------------
__global__ __launch_bounds__(256) void ln_kernel(
    const float* __restrict__ m,
    const float* __restrict__ lns,
    const float* __restrict__ lnb,
    unsigned short* __restrict__ xn)
{
    int tid = threadIdx.x;
    int lane = tid & 63, wave = tid >> 6;
    int r = blockIdx.x * 4 + wave;          // r = s*L + l
    int s = r / L_NR, l = r % L_NR;

    float4 x = ((const float4*)(m + (size_t)r * D_))[lane];

    float sum = x.x + x.y + x.z + x.w;
    float ss  = x.x*x.x + x.y*x.y + x.z*x.z + x.w*x.w;
#pragma unroll
    for (int off = 32; off > 0; off >>= 1) {
        sum += __shfl_xor(sum, off, 64);
        ss  += __shfl_xor(ss,  off, 64);
    }
    float mean = sum * (1.0f/256.0f);
    float var  = ss  * (1.0f/256.0f) - mean * mean;
    float rstd = rsqrtf(fmaxf(var, 0.0f) + 1e-5f);

    float4 sc = ((const float4*)lns)[lane];
    float4 bi = ((const float4*)lnb)[lane];

    float y0 = (x.x - mean) * rstd * sc.x + bi.x;
    float y1 = (x.y - mean) * rstd * sc.y + bi.y;
    float y2 = (x.z - mean) * rstd * sc.z + bi.z;
    float y3 = (x.w - mean) * rstd * sc.w + bi.w;

    uint2 w;
    w.x = f2b(y0) | (f2b(y1) << 16);
    w.y = f2b(y2) | (f2b(y3) << 16);
    *(uint2*)(xn + ((size_t)l * S_NS + s) * D_ + lane * 4) = w;
}

// ------------- Fused projections + attention per (l,h) -------------
// Round-6: one block computes Q/K/V/G slices for its (l,h) via 4 mini-GEMMs
// (256x32 out, B-tile 16 KB LDS, proj's swizzle with 1-bit nq), writes Q/K to
// LDS [s][40] (attn's exact layout), V to swizzled V^T LDS, and keeps G in
// registers: proj-acc (s=wave*32+mt*16+quad*4+r, c=nt*16+l16) == exactly the
// (s,c) this lane needs in the attn epilogue (mt=qt). Then round-3 online-
// softmax attention verbatim (2 qt x 16 rows per wave). Eliminates the
// 100 MB qb/kb/vb/gb HBM round-trip, proj's transpose/store epilogue and
// attn's staging phase. All arithmetic bit-identical to the split version
// (same MFMA order, same rounding points) -> absmax must stay 0.004882812.
// LDS 74 KB -> 2 blocks/CU; (512,4) = 128 regs/wave (est. need ~110).
// Spill tripwire: FETCH_SIZE >> 100 MB.
#define QP 40    // Q/K LDS row stride (bf16 elems)
#define VP 264   // V^T LDS row stride (f16 elems)
#define VXOR(c) (((((c) >> 3) & 3)) << 4)

__global__ __launch_bounds__(512, 4) void fused_kernel(
    const unsigned short* __restrict__ xn,
    const unsigned short* __restrict__ wbf,   // 4 matrices, bf16, 65536 each
    const float* __restrict__ bg,
    const int* __restrict__ seq_pad, const int* __restrict__ res_pad,
    unsigned short* __restrict__ ctxg)
{
    __shared__ __align__(16) unsigned short Qlds[S_NS * QP];   // 20480 B
    __shared__ __align__(16) unsigned short Klds[S_NS * QP];   // 20480 B
    __shared__ __align__(16) unsigned short Vlds[C_ * VP];     // 16896 B
    __shared__ __align__(16) unsigned short Bl[8192];          // 16384 B
    __shared__ unsigned int padm[16];

    int tid  = threadIdx.x;
    int lane = tid & 63, wave = tid >> 6;       // 8 waves
    int quad = lane >> 4, l16 = lane & 15;

    // XCD regroup: hw = (l%8) + 8*((l/8)*8 + h): the 8 h-blocks of one l are
    // consecutive slots on ONE XCD -> xn rows (128 KB) stay in that L2.
    int hw   = blockIdx.x;
    int xcd  = hw & 7, slot = hw >> 3;
    int h    = slot & 7;
    int l    = (slot >> 3) * 8 + xcd;

    if (tid < 16) {
        unsigned int pm = 0;
        for (int mt = 0; mt < 16; ++mt)
            pm |= (seq_pad[mt * 16 + tid] != 0 ? 1u : 0u) << mt;
        padm[tid] = pm;
    }

    int row0 = l * 256 + wave * 32;
    const unsigned short* arow = xn + (size_t)(row0 + l16) * D_ + quad * 8;
    int swb = l16 ^ quad;
    const float qscale = 0.17677669529663687f;  // 1/sqrt(32)

    f32x4_t accg[2][2];                          // gate values, stay in regs

#pragma unroll
    for (int mat = 0; mat < 4; ++mat) {
        const unsigned short* W = wbf + (size_t)mat * 65536 + (size_t)(h * 32) * 256;

        // stage B chunk (32 n x 256 k): coalesced global, swizzled LDS
#pragma unroll
        for (int j = 0; j < 2; ++j) {
            int c  = j * 512 + tid;
            int n  = c >> 5, kk = c & 31;
            int ks = kk >> 2, kq = kk & 3;
            int sw = (n & 15) ^ kq ^ ((ks & 1) << 2);
            uint4 d = *(const uint4*)(W + n * 256 + kk * 8);
            *(uint4*)&Bl[ks * 1024 + ((n >> 4) & 1) * 512 + kq * 128 + sw * 8] = d;
        }
        __syncthreads();

        f32x4_t acc[2][2];
#pragma unroll
        for (int mt = 0; mt < 2; ++mt)
#pragma unroll
            for (int nt = 0; nt < 2; ++nt) acc[mt][nt] = (f32x4_t){0.f,0.f,0.f,0.f};

        bf16x8_t a_cur[2], a_nxt[2];
        a_cur[0] = *(const bf16x8_t*)(arow);
        a_cur[1] = *(const bf16x8_t*)(arow + 16 * D_);
#pragma unroll
        for (int ks = 0; ks < 8; ++ks) {
            if (ks < 7) {
                a_nxt[0] = *(const bf16x8_t*)(arow + (ks + 1) * 32);
                a_nxt[1] = *(const bf16x8_t*)(arow + 16 * D_ + (ks + 1) * 32);
            }
            int kbase = ks * 1024 + quad * 128 + (swb ^ ((ks & 1) << 2)) * 8;
#pragma unroll
            for (int nt = 0; nt < 2; ++nt) {
                bf16x8_t bfr = *(const bf16x8_t*)&Bl[kbase + nt * 512];
                acc[0][nt] = __builtin_amdgcn_mfma_f32_16x16x32_bf16(a_cur[0], bfr, acc[0][nt], 0, 0, 0);
                acc[1][nt] = __builtin_amdgcn_mfma_f32_16x16x32_bf16(a_cur[1], bfr, acc[1][nt], 0, 0, 0);
            }
            a_cur[0] = a_nxt[0]; a_cur[1] = a_nxt[1];
        }
        __syncthreads();   // all waves done with Bl; next mat may restage

        if (mat == 0) {          // Q: scale + bf16 -> Qlds[s][QP]
#pragma unroll
            for (int mt = 0; mt < 2; ++mt)
#pragma unroll
                for (int nt = 0; nt < 2; ++nt)
#pragma unroll
                    for (int r = 0; r < 4; ++r) {
                        int srow = wave * 32 + mt * 16 + quad * 4 + r;
                        Qlds[srow * QP + nt * 16 + l16] =
                            (unsigned short)f2b(acc[mt][nt][r] * qscale);
                    }
        } else if (mat == 1) {   // K: bf16 -> Klds[s][QP]
#pragma unroll
            for (int mt = 0; mt < 2; ++mt)
#pragma unroll
                for (int nt = 0; nt < 2; ++nt)
#pragma unroll
                    for (int r = 0; r < 4; ++r) {
                        int srow = wave * 32 + mt * 16 + quad * 4 + r;
                        Klds[srow * QP + nt * 16 + l16] =
                            (unsigned short)f2b(acc[mt][nt][r]);
                    }
        } else if (mat == 2) {   // V: f16 -> V^T LDS [c][s^VXOR], b64 packed
#pragma unroll
            for (int mt = 0; mt < 2; ++mt)
#pragma unroll
                for (int nt = 0; nt < 2; ++nt) {
                    int cc = nt * 16 + l16;
                    int s0 = wave * 32 + mt * 16 + quad * 4;
                    half4_t hv;
                    hv[0] = (_Float16)acc[mt][nt][0];
                    hv[1] = (_Float16)acc[mt][nt][1];
                    hv[2] = (_Float16)acc[mt][nt][2];
                    hv[3] = (_Float16)acc[mt][nt][3];
                    *(half4_t*)&Vlds[cc * VP + (s0 ^ VXOR(cc))] = hv;
                }
        } else {                 // G: sigmoid, round through bf16, keep in regs
#pragma unroll
            for (int mt = 0; mt < 2; ++mt)
#pragma unroll
                for (int nt = 0; nt < 2; ++nt) {
                    float bgn = bg[h * 32 + nt * 16 + l16];
#pragma unroll
                    for (int r = 0; r < 4; ++r)
                        accg[mt][nt][r] =
                            bflo(f2b(1.0f / (1.0f + __expf(-(acc[mt][nt][r] + bgn)))));
                }
        }
    }
    __syncthreads();   // K/V (cross-wave) complete before attention reads

    // ---------------- attention (round-3 structure, 2 qt x 16 rows/wave) ----
    unsigned int allm = 0xFFFFu;
#pragma unroll
    for (int i = 0; i < 16; ++i) allm &= padm[i];
    int flagall = (res_pad[l] != 0) || (allm == 0xFFFFu);

    unsigned int keep[4];
#pragma unroll
    for (int r = 0; r < 4; ++r)
        keep[r] = flagall ? 0xFFFFu : (~padm[quad * 4 + r] & 0xFFFFu);

    const float LOG2E = 1.4426950408889634f;
    int vx0 = VXOR(l16), vx1 = VXOR(16 + l16);

#pragma unroll
    for (int qt = 0; qt < 2; ++qt) {
        int sb = wave * 32 + qt * 16;

        bf16x8_t qf = *(const bf16x8_t*)(Qlds + (size_t)(sb + l16) * QP + quad * 8);

        float mk = -3.0e38f;
        float sp = 0.0f;
        f32x4_t c0 = (f32x4_t){0.f,0.f,0.f,0.f}, c1 = (f32x4_t){0.f,0.f,0.f,0.f};

#pragma unroll
        for (int g = 0; g < 2; ++g) {
            f32x4_t a[8];
#pragma unroll
            for (int j = 0; j < 8; ++j) {
                int kt = g * 8 + j;
                bf16x8_t kf = *(const bf16x8_t*)(Klds + (kt * 16 + l16) * QP + quad * 8);
                a[j] = __builtin_amdgcn_mfma_f32_16x16x32_bf16(kf, qf, (f32x4_t){0.f,0.f,0.f,0.f}, 0, 0, 0);
            }
            float p0 = fmaxf(fmaxf(a[0][0], a[0][1]), fmaxf(a[0][2], a[0][3]));
            float p1 = fmaxf(fmaxf(a[1][0], a[1][1]), fmaxf(a[1][2], a[1][3]));
            float p2 = fmaxf(fmaxf(a[2][0], a[2][1]), fmaxf(a[2][2], a[2][3]));
            float p3 = fmaxf(fmaxf(a[3][0], a[3][1]), fmaxf(a[3][2], a[3][3]));
            float p4 = fmaxf(fmaxf(a[4][0], a[4][1]), fmaxf(a[4][2], a[4][3]));
            float p5 = fmaxf(fmaxf(a[5][0], a[5][1]), fmaxf(a[5][2], a[5][3]));
            float p6 = fmaxf(fmaxf(a[6][0], a[6][1]), fmaxf(a[6][2], a[6][3]));
            float p7 = fmaxf(fmaxf(a[7][0], a[7][1]), fmaxf(a[7][2], a[7][3]));
            float gm = fmaxf(fmaxf(fmaxf(p0, p1), fmaxf(p2, p3)),
                             fmaxf(fmaxf(p4, p5), fmaxf(p6, p7)));
            gm = fmaxf(gm, __shfl_xor(gm, 16, 64));
            gm = fmaxf(gm, __shfl_xor(gm, 32, 64));
            float gmk = gm * LOG2E;

            bool need = gmk > mk + 11.0f;
            if (__any(need)) {
                float nmk = fmaxf(mk, gmk);
                float f = __builtin_amdgcn_exp2f(mk - nmk);
                mk = nmk;
                sp *= f;
#pragma unroll
                for (int r = 0; r < 4; ++r) {
                    float fr = __shfl(f, (lane & 48) | (quad * 4 + r), 64);
                    c0[r] *= fr; c1[r] *= fr;
                }
            }

            half4_t pf[8];
            float s0 = 0.f, s1 = 0.f, s2 = 0.f, s3 = 0.f;
#pragma unroll
            for (int j = 0; j < 8; ++j) {
                int kt = g * 8 + j;
                float e0 = __builtin_amdgcn_exp2f(a[j][0] * LOG2E - mk);
                float e1 = __builtin_amdgcn_exp2f(a[j][1] * LOG2E - mk);
                float e2 = __builtin_amdgcn_exp2f(a[j][2] * LOG2E - mk);
                float e3 = __builtin_amdgcn_exp2f(a[j][3] * LOG2E - mk);
                e0 = ((keep[0] >> kt) & 1u) ? e0 : 0.0f;
                e1 = ((keep[1] >> kt) & 1u) ? e1 : 0.0f;
                e2 = ((keep[2] >> kt) & 1u) ? e2 : 0.0f;
                e3 = ((keep[3] >> kt) & 1u) ? e3 : 0.0f;
                s0 += e0; s1 += e1; s2 += e2; s3 += e3;
                half4_t t;
                t[0] = (_Float16)e0; t[1] = (_Float16)e1;
                t[2] = (_Float16)e2; t[3] = (_Float16)e3;
                pf[j] = t;
            }
            sp += (s0 + s1) + (s2 + s3);

#pragma unroll
            for (int j = 0; j < 8; ++j) {
                int kt = g * 8 + j;
                int toff = kt * 16 + quad * 4;
                half4_t v0 = *(const half4_t*)(Vlds + l16 * VP        + (toff ^ vx0));
                half4_t v1 = *(const half4_t*)(Vlds + (16 + l16) * VP + (toff ^ vx1));
                c0 = __builtin_amdgcn_mfma_f32_16x16x16f16(pf[j], v0, c0, 0, 0, 0);
                c1 = __builtin_amdgcn_mfma_f32_16x16x16f16(pf[j], v1, c1, 0, 0, 0);
            }
        }

        sp += __shfl_xor(sp, 16, 64);
        sp += __shfl_xor(sp, 32, 64);
        float inv = 1.0f / sp;

#pragma unroll
        for (int r = 0; r < 4; ++r) {
            int s = sb + quad * 4 + r;
            float iv = __shfl(inv, (lane & 48) | (quad * 4 + r), 64);
            float g0 = accg[qt][0][r];
            float g1 = accg[qt][1][r];
            unsigned short* op = ctxg + (size_t)(l * S_NS + s) * D_ + h * C_;
            op[l16]      = (unsigned short)f2b(c0[r] * iv * g0);
            op[16 + l16] = (unsigned short)f2b(c1[r] * iv * g1);
        }
    }
}

// ------------- Output projection (LDS-B): ctxg @ wo^T + bo -> out fp32 (S,L,D) -------------
// Round-5 structure kept: (256,4) + depth-1 prefetch + XCD regroup.
__global__ __launch_bounds__(256, 4) void out_kernel(
    const unsigned short* __restrict__ ctxg,
    const unsigned short* __restrict__ wob,   // bf16 wo
    const float* __restrict__ bo,
    float* __restrict__ out)
{
    __shared__ __align__(16) unsigned short Bl[16384];   // 32 KB

    int tid  = threadIdx.x;
    int lane = tid & 63, wave = tid >> 6;
    int quad = lane >> 4, l16 = lane & 15;

    // --- XCD regroup: invert hw = l%8 + 8*((l/8)*4 + y) ---
    int hw   = blockIdx.y * 192 + blockIdx.x;   // dispatch index (x-fastest)
    int xcd  = hw & 7;
    int slot = hw >> 3;
    int y    = slot & 3;
    int l    = (slot >> 2) * 8 + xcd;

    int n0   = y * 64;
    const unsigned short* W = wob + (size_t)n0 * 256;

#pragma unroll
    for (int j = 0; j < 8; ++j) {
        int c  = j * 256 + tid;
        int n  = c >> 5, kk = c & 31;
        int ks = kk >> 2, kq = kk & 3;
        int sw = (n & 15) ^ kq ^ ((ks & 1) << 2);
        uint4 d = *(const uint4*)(W + n * 256 + kk * 8);
        *(uint4*)&Bl[ks * 2048 + (n >> 4) * 512 + kq * 128 + sw * 8] = d;
    }
    __syncthreads();

    int row0 = l * 256 + wave * 64;
    const unsigned short* arow = ctxg + (size_t)(row0 + l16) * D_ + quad * 8;

    f32x4_t acc[4][4];
#pragma unroll
    for (int mt = 0; mt < 4; ++mt)
#pragma unroll
        for (int nt = 0; nt < 4; ++nt) acc[mt][nt] = (f32x4_t){0.f,0.f,0.f,0.f};

    bf16x8_t a_cur[4], a_nxt[4];
#pragma unroll
    for (int mt = 0; mt < 4; ++mt) a_cur[mt] = *(const bf16x8_t*)(arow + mt * 16 * D_);

    int swb = l16 ^ quad;
#pragma unroll
    for (int ks = 0; ks < 8; ++ks) {
        if (ks < 7) {
#pragma unroll
            for (int mt = 0; mt < 4; ++mt)
                a_nxt[mt] = *(const bf16x8_t*)(arow + mt * 16 * D_ + (ks + 1) * 32);
        }
        int kbase = ks * 2048 + quad * 128 + (swb ^ ((ks & 1) << 2)) * 8;
#pragma unroll
        for (int nt = 0; nt < 4; ++nt) {
            bf16x8_t bfr = *(const bf16x8_t*)&Bl[kbase + nt * 512];
#pragma unroll
            for (int mt = 0; mt < 4; ++mt)
                acc[mt][nt] = __builtin_amdgcn_mfma_f32_16x16x32_bf16(a_cur[mt], bfr, acc[mt][nt], 0, 0, 0);
        }
#pragma unroll
        for (int mt = 0; mt < 4; ++mt) a_cur[mt] = a_nxt[mt];
    }

#pragma unroll
    for (int nt = 0; nt < 4; ++nt) {
        int n = n0 + nt * 16 + l16;
        float bias = bo[n];
#pragma unroll
        for (int mt = 0; mt < 4; ++mt) {
#pragma unroll
            for (int r = 0; r < 4; ++r) {
                int s = wave * 64 + mt * 16 + quad * 4 + r;
                out[((size_t)s * L_NR + l) * D_ + n] = acc[mt][nt][r] + bias;
            }
        }
    }
}

extern "C" void kernel_launch(void* const* d_in, const int* in_sizes, int n_in,
                              void* d_out, int out_size, void* d_ws, size_t ws_size,
                              hipStream_t stream) {
    const float* m     = (const float*)d_in[0];
    const int* seq_pad = (const int*)d_in[1];
    const int* res_pad = (const int*)d_in[2];
    const float* lns   = (const float*)d_in[3];
    const float* lnb   = (const float*)d_in[4];
    const float* wq    = (const float*)d_in[5];
    const float* wk    = (const float*)d_in[6];
    const float* wv    = (const float*)d_in[7];
    const float* wg    = (const float*)d_in[8];
    const float* bg    = (const float*)d_in[9];
    const float* wo    = (const float*)d_in[10];
    const float* bo    = (const float*)d_in[11];
    float* out         = (float*)d_out;

    const size_t NE = (size_t)L_NR * S_NS * D_;   // 12,582,912 elements
    unsigned short* xn   = (unsigned short*)d_ws; // bf16 (L,S,D)
    unsigned short* ctxg = xn + NE;               // bf16 (L,S,D) gated context
    unsigned short* wbf  = ctxg + NE;             // 5 x 65536 bf16 weights

    convw_kernel<<<dim3(64, 5), 256, 0, stream>>>(wq, wk, wv, wg, wo, wbf);
    ln_kernel<<<12288, 256, 0, stream>>>(m, lns, lnb, xn);
    fused_kernel<<<L_NR * H_, 512, 0, stream>>>(xn, wbf, bg, seq_pad, res_pad, ctxg);
    out_kernel<<<dim3(192, 4), 256, 0, stream>>>(ctxg, wbf + 4 * 65536, bo, out);
}

// Round 7
// 231.341 us; speedup vs baseline: 1.2110x; 1.1231x over previous
//
#include <hip/hip_runtime.h>
#include <stdint.h>

#define L_NR 192
#define S_NS 256
#define D_   256
#define H_   8
#define C_   32

typedef __bf16    bf16x8_t __attribute__((ext_vector_type(8)));
typedef _Float16  half4_t  __attribute__((ext_vector_type(4)));
typedef float     f32x4_t  __attribute__((ext_vector_type(4)));

__device__ __forceinline__ float bflo(unsigned int u) { return __uint_as_float(u << 16); }
__device__ __forceinline__ unsigned int f2b(float f) {
    unsigned int x = __float_as_uint(f);
    return (x + 0x7fffu + ((x >> 16) & 1u)) >> 16;   // RNE
}
__device__ __forceinline__ unsigned short f2h(float f) {
    union { _Float16 h; unsigned short u; } cv; cv.h = (_Float16)f; return cv.u;
}

// ---- Convert 5 fp32 weight matrices (256x256) to bf16 in workspace ----
__global__ __launch_bounds__(256) void convw_kernel(
    const float* __restrict__ wq, const float* __restrict__ wk,
    const float* __restrict__ wv, const float* __restrict__ wg,
    const float* __restrict__ wo, unsigned short* __restrict__ dst)
{
    int mat = blockIdx.y;
    const float* src = (mat == 0) ? wq : (mat == 1) ? wk : (mat == 2) ? wv
                     : (mat == 3) ? wg : wo;
    int i = (blockIdx.x * 256 + threadIdx.x) * 4;
    float4 v = *(const float4*)(src + i);
    uint2 w;
    w.x = f2b(v.x) | (f2b(v.y) << 16);
    w.y = f2b(v.z) | (f2b(v.w) << 16);
    *(uint2*)(dst + (size_t)mat * 65536 + i) = w;
}

// ---------------- LayerNorm: m fp32 (S,L,D) -> xn bf16 (L,S,D) ----------------
__global__ __launch_bounds__(256) void ln_kernel(
    const float* __restrict__ m,
    const float* __restrict__ lns,
    const float* __restrict__ lnb,
    unsigned short* __restrict__ xn)
{
    int tid = threadIdx.x;
    int lane = tid & 63, wave = tid >> 6;
    int r = blockIdx.x * 4 + wave;          // r = s*L + l
    int s = r / L_NR, l = r % L_NR;

    float4 x = ((const float4*)(m + (size_t)r * D_))[lane];

    float sum = x.x + x.y + x.z + x.w;
    float ss  = x.x*x.x + x.y*x.y + x.z*x.z + x.w*x.w;
#pragma unroll
    for (int off = 32; off > 0; off >>= 1) {
        sum += __shfl_xor(sum, off, 64);
        ss  += __shfl_xor(ss,  off, 64);
    }
    float mean = sum * (1.0f/256.0f);
    float var  = ss  * (1.0f/256.0f) - mean * mean;
    float rstd = rsqrtf(fmaxf(var, 0.0f) + 1e-5f);

    float4 sc = ((const float4*)lns)[lane];
    float4 bi = ((const float4*)lnb)[lane];

    float y0 = (x.x - mean) * rstd * sc.x + bi.x;
    float y1 = (x.y - mean) * rstd * sc.y + bi.y;
    float y2 = (x.z - mean) * rstd * sc.z + bi.z;
    float y3 = (x.w - mean) * rstd * sc.w + bi.w;

    uint2 w;
    w.x = f2b(y0) | (f2b(y1) << 16);
    w.y = f2b(y2) | (f2b(y3) << 16);
    *(uint2*)(xn + ((size_t)l * S_NS + s) * D_ + lane * 4) = w;
}

// ------------- Fused projections + attention per (l,h) -------------
// Round-7: stage ALL FOUR 32x256 B-tiles once (64 KB), then ONE K-outer GEMM:
// per ks the A-pair is loaded ONCE and applied to all 4 mats (was: 4 separate
// GEMMs re-loading A 4x from global with 2 barriers each). A global loads
// 64->16 per wave; barriers 9->2. acc[4][2][2] = 64 accum regs, statically
// indexed. LDS 120.6 KB -> 1 block/CU; (512,2) = 256-reg budget, no spill
// risk. Per-accumulator MFMA order unchanged -> absmax must stay 0.004882812.
#define QP 40    // Q/K LDS row stride (bf16 elems)
#define VP 264   // V^T LDS row stride (f16 elems)
#define VXOR(c) (((((c) >> 3) & 3)) << 4)

__global__ __launch_bounds__(512, 2) void fused_kernel(
    const unsigned short* __restrict__ xn,
    const unsigned short* __restrict__ wbf,   // 4 matrices, bf16, 65536 each
    const float* __restrict__ bg,
    const int* __restrict__ seq_pad, const int* __restrict__ res_pad,
    unsigned short* __restrict__ ctxg)
{
    __shared__ __align__(16) unsigned short Bst[4 * 8192];     // 65536 B
    __shared__ __align__(16) unsigned short Qlds[S_NS * QP];   // 20480 B
    __shared__ __align__(16) unsigned short Klds[S_NS * QP];   // 20480 B
    __shared__ __align__(16) unsigned short Vlds[C_ * VP];     // 16896 B
    __shared__ unsigned int padm[16];

    int tid  = threadIdx.x;
    int lane = tid & 63, wave = tid >> 6;       // 8 waves
    int quad = lane >> 4, l16 = lane & 15;

    // XCD regroup: the 8 h-blocks of one l are consecutive slots on ONE XCD.
    int hw   = blockIdx.x;
    int xcd  = hw & 7, slot = hw >> 3;
    int h    = slot & 7;
    int l    = (slot >> 3) * 8 + xcd;

    if (tid < 16) {
        unsigned int pm = 0;
        for (int mt = 0; mt < 16; ++mt)
            pm |= (seq_pad[mt * 16 + tid] != 0 ? 1u : 0u) << mt;
        padm[tid] = pm;
    }

    int row0 = l * 256 + wave * 32;
    const unsigned short* arow = xn + (size_t)(row0 + l16) * D_ + quad * 8;

    // early A prefetch for ks=0 (completes during staging)
    bf16x8_t a_cur[2], a_nxt[2];
    a_cur[0] = *(const bf16x8_t*)(arow);
    a_cur[1] = *(const bf16x8_t*)(arow + 16 * D_);

    // stage all 4 B tiles (32 n x 256 k each): coalesced global, swizzled LDS
    const unsigned short* Wh = wbf + (size_t)(h * 32) * 256;
#pragma unroll
    for (int j = 0; j < 8; ++j) {
        int mat = j >> 1;
        int c  = (j & 1) * 512 + tid;
        int n  = c >> 5, kk = c & 31;
        int ks = kk >> 2, kq = kk & 3;
        int sw = (n & 15) ^ kq ^ ((ks & 1) << 2);
        uint4 d = *(const uint4*)(Wh + (size_t)mat * 65536 + n * 256 + kk * 8);
        *(uint4*)&Bst[mat * 8192 + ks * 1024 + (n >> 4) * 512 + kq * 128 + sw * 8] = d;
    }
    __syncthreads();

    f32x4_t acc[4][2][2];
#pragma unroll
    for (int mat = 0; mat < 4; ++mat)
#pragma unroll
        for (int mt = 0; mt < 2; ++mt)
#pragma unroll
            for (int nt = 0; nt < 2; ++nt) acc[mat][mt][nt] = (f32x4_t){0.f,0.f,0.f,0.f};

    int swb = l16 ^ quad;
#pragma unroll
    for (int ks = 0; ks < 8; ++ks) {
        if (ks < 7) {
            a_nxt[0] = *(const bf16x8_t*)(arow + (ks + 1) * 32);
            a_nxt[1] = *(const bf16x8_t*)(arow + 16 * D_ + (ks + 1) * 32);
        }
        int kbase = ks * 1024 + quad * 128 + (swb ^ ((ks & 1) << 2)) * 8;
#pragma unroll
        for (int mat = 0; mat < 4; ++mat) {
#pragma unroll
            for (int nt = 0; nt < 2; ++nt) {
                bf16x8_t bfr = *(const bf16x8_t*)&Bst[mat * 8192 + kbase + nt * 512];
                acc[mat][0][nt] = __builtin_amdgcn_mfma_f32_16x16x32_bf16(a_cur[0], bfr, acc[mat][0][nt], 0, 0, 0);
                acc[mat][1][nt] = __builtin_amdgcn_mfma_f32_16x16x32_bf16(a_cur[1], bfr, acc[mat][1][nt], 0, 0, 0);
            }
        }
        a_cur[0] = a_nxt[0]; a_cur[1] = a_nxt[1];
    }

    // ---- epilogues (write Q/K/V LDS + gate regs; no aliasing with Bst -> no barrier) ----
    const float qscale = 0.17677669529663687f;  // 1/sqrt(32)
    f32x4_t accg[2][2];

#pragma unroll
    for (int mt = 0; mt < 2; ++mt)
#pragma unroll
        for (int nt = 0; nt < 2; ++nt) {
#pragma unroll
            for (int r = 0; r < 4; ++r) {
                int srow = wave * 32 + mt * 16 + quad * 4 + r;
                Qlds[srow * QP + nt * 16 + l16] = (unsigned short)f2b(acc[0][mt][nt][r] * qscale);
                Klds[srow * QP + nt * 16 + l16] = (unsigned short)f2b(acc[1][mt][nt][r]);
            }
            // V: f16, transposed + swizzled, b64 packed
            int cc = nt * 16 + l16;
            int s0 = wave * 32 + mt * 16 + quad * 4;
            half4_t hv;
            hv[0] = (_Float16)acc[2][mt][nt][0];
            hv[1] = (_Float16)acc[2][mt][nt][1];
            hv[2] = (_Float16)acc[2][mt][nt][2];
            hv[3] = (_Float16)acc[2][mt][nt][3];
            *(half4_t*)&Vlds[cc * VP + (s0 ^ VXOR(cc))] = hv;
            // G: sigmoid, round through bf16, keep in regs
            float bgn = bg[h * 32 + nt * 16 + l16];
#pragma unroll
            for (int r = 0; r < 4; ++r)
                accg[mt][nt][r] = bflo(f2b(1.0f / (1.0f + __expf(-(acc[3][mt][nt][r] + bgn)))));
        }
    __syncthreads();   // K/V/Q (cross-wave) complete before attention reads

    // ---------------- attention (2 qt x 16 rows/wave, online softmax) ----
    unsigned int allm = 0xFFFFu;
#pragma unroll
    for (int i = 0; i < 16; ++i) allm &= padm[i];
    int flagall = (res_pad[l] != 0) || (allm == 0xFFFFu);

    unsigned int keep[4];
#pragma unroll
    for (int r = 0; r < 4; ++r)
        keep[r] = flagall ? 0xFFFFu : (~padm[quad * 4 + r] & 0xFFFFu);

    const float LOG2E = 1.4426950408889634f;
    int vx0 = VXOR(l16), vx1 = VXOR(16 + l16);

#pragma unroll
    for (int qt = 0; qt < 2; ++qt) {
        int sb = wave * 32 + qt * 16;

        bf16x8_t qf = *(const bf16x8_t*)(Qlds + (size_t)(sb + l16) * QP + quad * 8);

        float mk = -3.0e38f;
        float sp = 0.0f;
        f32x4_t c0 = (f32x4_t){0.f,0.f,0.f,0.f}, c1 = (f32x4_t){0.f,0.f,0.f,0.f};

#pragma unroll
        for (int g = 0; g < 2; ++g) {
            f32x4_t a[8];
#pragma unroll
            for (int j = 0; j < 8; ++j) {
                int kt = g * 8 + j;
                bf16x8_t kf = *(const bf16x8_t*)(Klds + (kt * 16 + l16) * QP + quad * 8);
                a[j] = __builtin_amdgcn_mfma_f32_16x16x32_bf16(kf, qf, (f32x4_t){0.f,0.f,0.f,0.f}, 0, 0, 0);
            }
            float p0 = fmaxf(fmaxf(a[0][0], a[0][1]), fmaxf(a[0][2], a[0][3]));
            float p1 = fmaxf(fmaxf(a[1][0], a[1][1]), fmaxf(a[1][2], a[1][3]));
            float p2 = fmaxf(fmaxf(a[2][0], a[2][1]), fmaxf(a[2][2], a[2][3]));
            float p3 = fmaxf(fmaxf(a[3][0], a[3][1]), fmaxf(a[3][2], a[3][3]));
            float p4 = fmaxf(fmaxf(a[4][0], a[4][1]), fmaxf(a[4][2], a[4][3]));
            float p5 = fmaxf(fmaxf(a[5][0], a[5][1]), fmaxf(a[5][2], a[5][3]));
            float p6 = fmaxf(fmaxf(a[6][0], a[6][1]), fmaxf(a[6][2], a[6][3]));
            float p7 = fmaxf(fmaxf(a[7][0], a[7][1]), fmaxf(a[7][2], a[7][3]));
            float gm = fmaxf(fmaxf(fmaxf(p0, p1), fmaxf(p2, p3)),
                             fmaxf(fmaxf(p4, p5), fmaxf(p6, p7)));
            gm = fmaxf(gm, __shfl_xor(gm, 16, 64));
            gm = fmaxf(gm, __shfl_xor(gm, 32, 64));
            float gmk = gm * LOG2E;

            bool need = gmk > mk + 11.0f;
            if (__any(need)) {
                float nmk = fmaxf(mk, gmk);
                float f = __builtin_amdgcn_exp2f(mk - nmk);
                mk = nmk;
                sp *= f;
#pragma unroll
                for (int r = 0; r < 4; ++r) {
                    float fr = __shfl(f, (lane & 48) | (quad * 4 + r), 64);
                    c0[r] *= fr; c1[r] *= fr;
                }
            }

            half4_t pf[8];
            float s0 = 0.f, s1 = 0.f, s2 = 0.f, s3 = 0.f;
#pragma unroll
            for (int j = 0; j < 8; ++j) {
                int kt = g * 8 + j;
                float e0 = __builtin_amdgcn_exp2f(a[j][0] * LOG2E - mk);
                float e1 = __builtin_amdgcn_exp2f(a[j][1] * LOG2E - mk);
                float e2 = __builtin_amdgcn_exp2f(a[j][2] * LOG2E - mk);
                float e3 = __builtin_amdgcn_exp2f(a[j][3] * LOG2E - mk);
                e0 = ((keep[0] >> kt) & 1u) ? e0 : 0.0f;
                e1 = ((keep[1] >> kt) & 1u) ? e1 : 0.0f;
                e2 = ((keep[2] >> kt) & 1u) ? e2 : 0.0f;
                e3 = ((keep[3] >> kt) & 1u) ? e3 : 0.0f;
                s0 += e0; s1 += e1; s2 += e2; s3 += e3;
                half4_t t;
                t[0] = (_Float16)e0; t[1] = (_Float16)e1;
                t[2] = (_Float16)e2; t[3] = (_Float16)e3;
                pf[j] = t;
            }
            sp += (s0 + s1) + (s2 + s3);

#pragma unroll
            for (int j = 0; j < 8; ++j) {
                int kt = g * 8 + j;
                int toff = kt * 16 + quad * 4;
                half4_t v0 = *(const half4_t*)(Vlds + l16 * VP        + (toff ^ vx0));
                half4_t v1 = *(const half4_t*)(Vlds + (16 + l16) * VP + (toff ^ vx1));
                c0 = __builtin_amdgcn_mfma_f32_16x16x16f16(pf[j], v0, c0, 0, 0, 0);
                c1 = __builtin_amdgcn_mfma_f32_16x16x16f16(pf[j], v1, c1, 0, 0, 0);
            }
        }

        sp += __shfl_xor(sp, 16, 64);
        sp += __shfl_xor(sp, 32, 64);
        float inv = 1.0f / sp;

#pragma unroll
        for (int r = 0; r < 4; ++r) {
            int s = sb + quad * 4 + r;
            float iv = __shfl(inv, (lane & 48) | (quad * 4 + r), 64);
            float g0 = accg[qt][0][r];
            float g1 = accg[qt][1][r];
            unsigned short* op = ctxg + (size_t)(l * S_NS + s) * D_ + h * C_;
            op[l16]      = (unsigned short)f2b(c0[r] * iv * g0);
            op[16 + l16] = (unsigned short)f2b(c1[r] * iv * g1);
        }
    }
}

// ------------- Output projection (LDS-B): ctxg @ wo^T + bo -> out fp32 (S,L,D) -------------
// Round-5 structure kept: (256,4) + depth-1 prefetch + XCD regroup.
__global__ __launch_bounds__(256, 4) void out_kernel(
    const unsigned short* __restrict__ ctxg,
    const unsigned short* __restrict__ wob,   // bf16 wo
    const float* __restrict__ bo,
    float* __restrict__ out)
{
    __shared__ __align__(16) unsigned short Bl[16384];   // 32 KB

    int tid  = threadIdx.x;
    int lane = tid & 63, wave = tid >> 6;
    int quad = lane >> 4, l16 = lane & 15;

    // --- XCD regroup: invert hw = l%8 + 8*((l/8)*4 + y) ---
    int hw   = blockIdx.y * 192 + blockIdx.x;   // dispatch index (x-fastest)
    int xcd  = hw & 7;
    int slot = hw >> 3;
    int y    = slot & 3;
    int l    = (slot >> 2) * 8 + xcd;

    int n0   = y * 64;
    const unsigned short* W = wob + (size_t)n0 * 256;

#pragma unroll
    for (int j = 0; j < 8; ++j) {
        int c  = j * 256 + tid;
        int n  = c >> 5, kk = c & 31;
        int ks = kk >> 2, kq = kk & 3;
        int sw = (n & 15) ^ kq ^ ((ks & 1) << 2);
        uint4 d = *(const uint4*)(W + n * 256 + kk * 8);
        *(uint4*)&Bl[ks * 2048 + (n >> 4) * 512 + kq * 128 + sw * 8] = d;
    }
    __syncthreads();

    int row0 = l * 256 + wave * 64;
    const unsigned short* arow = ctxg + (size_t)(row0 + l16) * D_ + quad * 8;

    f32x4_t acc[4][4];
#pragma unroll
    for (int mt = 0; mt < 4; ++mt)
#pragma unroll
        for (int nt = 0; nt < 4; ++nt) acc[mt][nt] = (f32x4_t){0.f,0.f,0.f,0.f};

    bf16x8_t a_cur[4], a_nxt[4];
#pragma unroll
    for (int mt = 0; mt < 4; ++mt) a_cur[mt] = *(const bf16x8_t*)(arow + mt * 16 * D_);

    int swb = l16 ^ quad;
#pragma unroll
    for (int ks = 0; ks < 8; ++ks) {
        if (ks < 7) {
#pragma unroll
            for (int mt = 0; mt < 4; ++mt)
                a_nxt[mt] = *(const bf16x8_t*)(arow + mt * 16 * D_ + (ks + 1) * 32);
        }
        int kbase = ks * 2048 + quad * 128 + (swb ^ ((ks & 1) << 2)) * 8;
#pragma unroll
        for (int nt = 0; nt < 4; ++nt) {
            bf16x8_t bfr = *(const bf16x8_t*)&Bl[kbase + nt * 512];
#pragma unroll
            for (int mt = 0; mt < 4; ++mt)
                acc[mt][nt] = __builtin_amdgcn_mfma_f32_16x16x32_bf16(a_cur[mt], bfr, acc[mt][nt], 0, 0, 0);
        }
#pragma unroll
        for (int mt = 0; mt < 4; ++mt) a_cur[mt] = a_nxt[mt];
    }

#pragma unroll
    for (int nt = 0; nt < 4; ++nt) {
        int n = n0 + nt * 16 + l16;
        float bias = bo[n];
#pragma unroll
        for (int mt = 0; mt < 4; ++mt) {
#pragma unroll
            for (int r = 0; r < 4; ++r) {
                int s = wave * 64 + mt * 16 + quad * 4 + r;
                out[((size_t)s * L_NR + l) * D_ + n] = acc[mt][nt][r] + bias;
            }
        }
    }
}

extern "C" void kernel_launch(void* const* d_in, const int* in_sizes, int n_in,
                              void* d_out, int out_size, void* d_ws, size_t ws_size,
                              hipStream_t stream) {
    const float* m     = (const float*)d_in[0];
    const int* seq_pad = (const int*)d_in[1];
    const int* res_pad = (const int*)d_in[2];
    const float* lns   = (const float*)d_in[3];
    const float* lnb   = (const float*)d_in[4];
    const float* wq    = (const float*)d_in[5];
    const float* wk    = (const float*)d_in[6];
    const float* wv    = (const float*)d_in[7];
    const float* wg    = (const float*)d_in[8];
    const float* bg    = (const float*)d_in[9];
    const float* wo    = (const float*)d_in[10];
    const float* bo    = (const float*)d_in[11];
    float* out         = (float*)d_out;

    const size_t NE = (size_t)L_NR * S_NS * D_;   // 12,582,912 elements
    unsigned short* xn   = (unsigned short*)d_ws; // bf16 (L,S,D)
    unsigned short* ctxg = xn + NE;               // bf16 (L,S,D) gated context
    unsigned short* wbf  = ctxg + NE;             // 5 x 65536 bf16 weights

    convw_kernel<<<dim3(64, 5), 256, 0, stream>>>(wq, wk, wv, wg, wo, wbf);
    ln_kernel<<<12288, 256, 0, stream>>>(m, lns, lnb, xn);
    fused_kernel<<<L_NR * H_, 512, 0, stream>>>(xn, wbf, bg, seq_pad, res_pad, ctxg);
    out_kernel<<<dim3(192, 4), 256, 0, stream>>>(ctxg, wbf + 4 * 65536, bo, out);
}

// Round 8
// 210.310 us; speedup vs baseline: 1.3321x; 1.1000x over previous
//
#include <hip/hip_runtime.h>
#include <stdint.h>

#define L_NR 192
#define S_NS 256
#define D_   256
#define H_   8
#define C_   32

typedef __bf16    bf16x8_t __attribute__((ext_vector_type(8)));
typedef _Float16  half4_t  __attribute__((ext_vector_type(4)));
typedef float     f32x4_t  __attribute__((ext_vector_type(4)));

__device__ __forceinline__ float bflo(unsigned int u) { return __uint_as_float(u << 16); }
__device__ __forceinline__ unsigned int f2b(float f) {
    unsigned int x = __float_as_uint(f);
    return (x + 0x7fffu + ((x >> 16) & 1u)) >> 16;   // RNE
}
__device__ __forceinline__ unsigned short f2h(float f) {
    union { _Float16 h; unsigned short u; } cv; cv.h = (_Float16)f; return cv.u;
}

// ---- Convert 5 fp32 weight matrices (256x256) to bf16 in workspace ----
__global__ __launch_bounds__(256) void convw_kernel(
    const float* __restrict__ wq, const float* __restrict__ wk,
    const float* __restrict__ wv, const float* __restrict__ wg,
    const float* __restrict__ wo, unsigned short* __restrict__ dst)
{
    int mat = blockIdx.y;
    const float* src = (mat == 0) ? wq : (mat == 1) ? wk : (mat == 2) ? wv
                     : (mat == 3) ? wg : wo;
    int i = (blockIdx.x * 256 + threadIdx.x) * 4;
    float4 v = *(const float4*)(src + i);
    uint2 w;
    w.x = f2b(v.x) | (f2b(v.y) << 16);
    w.y = f2b(v.z) | (f2b(v.w) << 16);
    *(uint2*)(dst + (size_t)mat * 65536 + i) = w;
}

// ---------------- LayerNorm: m fp32 (S,L,D) -> xn bf16 (L,S,D) ----------------
__global__ __launch_bounds__(256) void ln_kernel(
    const float* __restrict__ m,
    const float* __restrict__ lns,
    const float* __restrict__ lnb,
    unsigned short* __restrict__ xn)
{
    int tid = threadIdx.x;
    int lane = tid & 63, wave = tid >> 6;
    int r = blockIdx.x * 4 + wave;          // r = s*L + l
    int s = r / L_NR, l = r % L_NR;

    float4 x = ((const float4*)(m + (size_t)r * D_))[lane];

    float sum = x.x + x.y + x.z + x.w;
    float ss  = x.x*x.x + x.y*x.y + x.z*x.z + x.w*x.w;
#pragma unroll
    for (int off = 32; off > 0; off >>= 1) {
        sum += __shfl_xor(sum, off, 64);
        ss  += __shfl_xor(ss,  off, 64);
    }
    float mean = sum * (1.0f/256.0f);
    float var  = ss  * (1.0f/256.0f) - mean * mean;
    float rstd = rsqrtf(fmaxf(var, 0.0f) + 1e-5f);

    float4 sc = ((const float4*)lns)[lane];
    float4 bi = ((const float4*)lnb)[lane];

    float y0 = (x.x - mean) * rstd * sc.x + bi.x;
    float y1 = (x.y - mean) * rstd * sc.y + bi.y;
    float y2 = (x.z - mean) * rstd * sc.z + bi.z;
    float y3 = (x.w - mean) * rstd * sc.w + bi.w;

    uint2 w;
    w.x = f2b(y0) | (f2b(y1) << 16);
    w.y = f2b(y2) | (f2b(y3) << 16);
    *(uint2*)(xn + ((size_t)l * S_NS + s) * D_ + lane * 4) = w;
}

// ------------- Fused projections + attention per (l,h) -------------
// Round-8: LDS UNION. Bst (64 KB) is dead after the GEMM loop; Q/K/V LDS
// (57.9 KB) is only written after it -> overlay them in one 64 KB region.
// LDS 121 -> 64.2 KB => 2 blocks/CU (was 1): barrier drains of one block
// overlap the other block's compute; 4 waves/SIMD (was 2).
// __launch_bounds__(512,4): 128-reg cap. True per-phase peak ~95-100 (GEMM:
// 64 acc + ~30 arch; attention: acc dead, unified RF reuses it) -> no spill
// expected (r1/r2 spilled because true need was 160-190).
// Cost: +1 barrier (after last Bst read, before Q/K/V overwrite).
// Math order unchanged -> absmax must stay 0.004882812.
// Spill tripwire: FETCH_SIZE >> 50 MB.
#define QP 40    // Q/K LDS row stride (bf16 elems)
#define VP 264   // V^T LDS row stride (f16 elems)
#define VXOR(c) (((((c) >> 3) & 3)) << 4)

__global__ __launch_bounds__(512, 4) void fused_kernel(
    const unsigned short* __restrict__ xn,
    const unsigned short* __restrict__ wbf,   // 4 matrices, bf16, 65536 each
    const float* __restrict__ bg,
    const int* __restrict__ seq_pad, const int* __restrict__ res_pad,
    unsigned short* __restrict__ ctxg)
{
    __shared__ __align__(16) unsigned char SM[65536];   // union: Bst | {Q,K,V}
    __shared__ unsigned int padm[16];

    unsigned short* Bst  = (unsigned short*)SM;               // 65536 B (GEMM phase)
    unsigned short* Qlds = (unsigned short*)SM;               // 20480 B (attn phase)
    unsigned short* Klds = (unsigned short*)(SM + 20480);     // 20480 B
    unsigned short* Vlds = (unsigned short*)(SM + 40960);     // 16896 B (ends 57856)

    int tid  = threadIdx.x;
    int lane = tid & 63, wave = tid >> 6;       // 8 waves
    int quad = lane >> 4, l16 = lane & 15;

    // XCD regroup: the 8 h-blocks of one l are consecutive slots on ONE XCD.
    int hw   = blockIdx.x;
    int xcd  = hw & 7, slot = hw >> 3;
    int h    = slot & 7;
    int l    = (slot >> 3) * 8 + xcd;

    if (tid < 16) {
        unsigned int pm = 0;
        for (int mt = 0; mt < 16; ++mt)
            pm |= (seq_pad[mt * 16 + tid] != 0 ? 1u : 0u) << mt;
        padm[tid] = pm;
    }

    int row0 = l * 256 + wave * 32;
    const unsigned short* arow = xn + (size_t)(row0 + l16) * D_ + quad * 8;

    // early A prefetch for ks=0 (completes during staging)
    bf16x8_t a_cur[2], a_nxt[2];
    a_cur[0] = *(const bf16x8_t*)(arow);
    a_cur[1] = *(const bf16x8_t*)(arow + 16 * D_);

    // stage all 4 B tiles (32 n x 256 k each): coalesced global, swizzled LDS
    const unsigned short* Wh = wbf + (size_t)(h * 32) * 256;
#pragma unroll
    for (int j = 0; j < 8; ++j) {
        int mat = j >> 1;
        int c  = (j & 1) * 512 + tid;
        int n  = c >> 5, kk = c & 31;
        int ks = kk >> 2, kq = kk & 3;
        int sw = (n & 15) ^ kq ^ ((ks & 1) << 2);
        uint4 d = *(const uint4*)(Wh + (size_t)mat * 65536 + n * 256 + kk * 8);
        *(uint4*)&Bst[mat * 8192 + ks * 1024 + (n >> 4) * 512 + kq * 128 + sw * 8] = d;
    }
    __syncthreads();

    f32x4_t acc[4][2][2];
#pragma unroll
    for (int mat = 0; mat < 4; ++mat)
#pragma unroll
        for (int mt = 0; mt < 2; ++mt)
#pragma unroll
            for (int nt = 0; nt < 2; ++nt) acc[mat][mt][nt] = (f32x4_t){0.f,0.f,0.f,0.f};

    int swb = l16 ^ quad;
#pragma unroll
    for (int ks = 0; ks < 8; ++ks) {
        if (ks < 7) {
            a_nxt[0] = *(const bf16x8_t*)(arow + (ks + 1) * 32);
            a_nxt[1] = *(const bf16x8_t*)(arow + 16 * D_ + (ks + 1) * 32);
        }
        int kbase = ks * 1024 + quad * 128 + (swb ^ ((ks & 1) << 2)) * 8;
#pragma unroll
        for (int mat = 0; mat < 4; ++mat) {
#pragma unroll
            for (int nt = 0; nt < 2; ++nt) {
                bf16x8_t bfr = *(const bf16x8_t*)&Bst[mat * 8192 + kbase + nt * 512];
                acc[mat][0][nt] = __builtin_amdgcn_mfma_f32_16x16x32_bf16(a_cur[0], bfr, acc[mat][0][nt], 0, 0, 0);
                acc[mat][1][nt] = __builtin_amdgcn_mfma_f32_16x16x32_bf16(a_cur[1], bfr, acc[mat][1][nt], 0, 0, 0);
            }
        }
        a_cur[0] = a_nxt[0]; a_cur[1] = a_nxt[1];
    }
    __syncthreads();   // ALL waves done reading Bst before Q/K/V overwrite it

    // ---- epilogues: write Q/K/V into the union region + gate regs ----
    const float qscale = 0.17677669529663687f;  // 1/sqrt(32)
    f32x4_t accg[2][2];

#pragma unroll
    for (int mt = 0; mt < 2; ++mt)
#pragma unroll
        for (int nt = 0; nt < 2; ++nt) {
#pragma unroll
            for (int r = 0; r < 4; ++r) {
                int srow = wave * 32 + mt * 16 + quad * 4 + r;
                Qlds[srow * QP + nt * 16 + l16] = (unsigned short)f2b(acc[0][mt][nt][r] * qscale);
                Klds[srow * QP + nt * 16 + l16] = (unsigned short)f2b(acc[1][mt][nt][r]);
            }
            // V: f16, transposed + swizzled, b64 packed
            int cc = nt * 16 + l16;
            int s0 = wave * 32 + mt * 16 + quad * 4;
            half4_t hv;
            hv[0] = (_Float16)acc[2][mt][nt][0];
            hv[1] = (_Float16)acc[2][mt][nt][1];
            hv[2] = (_Float16)acc[2][mt][nt][2];
            hv[3] = (_Float16)acc[2][mt][nt][3];
            *(half4_t*)&Vlds[cc * VP + (s0 ^ VXOR(cc))] = hv;
            // G: sigmoid, round through bf16, keep in regs
            float bgn = bg[h * 32 + nt * 16 + l16];
#pragma unroll
            for (int r = 0; r < 4; ++r)
                accg[mt][nt][r] = bflo(f2b(1.0f / (1.0f + __expf(-(acc[3][mt][nt][r] + bgn)))));
        }
    __syncthreads();   // K/V/Q (cross-wave) complete before attention reads

    // ---------------- attention (2 qt x 16 rows/wave, online softmax) ----
    unsigned int allm = 0xFFFFu;
#pragma unroll
    for (int i = 0; i < 16; ++i) allm &= padm[i];
    int flagall = (res_pad[l] != 0) || (allm == 0xFFFFu);

    unsigned int keep[4];
#pragma unroll
    for (int r = 0; r < 4; ++r)
        keep[r] = flagall ? 0xFFFFu : (~padm[quad * 4 + r] & 0xFFFFu);

    const float LOG2E = 1.4426950408889634f;
    int vx0 = VXOR(l16), vx1 = VXOR(16 + l16);

#pragma unroll
    for (int qt = 0; qt < 2; ++qt) {
        int sb = wave * 32 + qt * 16;

        bf16x8_t qf = *(const bf16x8_t*)(Qlds + (size_t)(sb + l16) * QP + quad * 8);

        float mk = -3.0e38f;
        float sp = 0.0f;
        f32x4_t c0 = (f32x4_t){0.f,0.f,0.f,0.f}, c1 = (f32x4_t){0.f,0.f,0.f,0.f};

#pragma unroll
        for (int g = 0; g < 2; ++g) {
            f32x4_t a[8];
#pragma unroll
            for (int j = 0; j < 8; ++j) {
                int kt = g * 8 + j;
                bf16x8_t kf = *(const bf16x8_t*)(Klds + (kt * 16 + l16) * QP + quad * 8);
                a[j] = __builtin_amdgcn_mfma_f32_16x16x32_bf16(kf, qf, (f32x4_t){0.f,0.f,0.f,0.f}, 0, 0, 0);
            }
            float p0 = fmaxf(fmaxf(a[0][0], a[0][1]), fmaxf(a[0][2], a[0][3]));
            float p1 = fmaxf(fmaxf(a[1][0], a[1][1]), fmaxf(a[1][2], a[1][3]));
            float p2 = fmaxf(fmaxf(a[2][0], a[2][1]), fmaxf(a[2][2], a[2][3]));
            float p3 = fmaxf(fmaxf(a[3][0], a[3][1]), fmaxf(a[3][2], a[3][3]));
            float p4 = fmaxf(fmaxf(a[4][0], a[4][1]), fmaxf(a[4][2], a[4][3]));
            float p5 = fmaxf(fmaxf(a[5][0], a[5][1]), fmaxf(a[5][2], a[5][3]));
            float p6 = fmaxf(fmaxf(a[6][0], a[6][1]), fmaxf(a[6][2], a[6][3]));
            float p7 = fmaxf(fmaxf(a[7][0], a[7][1]), fmaxf(a[7][2], a[7][3]));
            float gm = fmaxf(fmaxf(fmaxf(p0, p1), fmaxf(p2, p3)),
                             fmaxf(fmaxf(p4, p5), fmaxf(p6, p7)));
            gm = fmaxf(gm, __shfl_xor(gm, 16, 64));
            gm = fmaxf(gm, __shfl_xor(gm, 32, 64));
            float gmk = gm * LOG2E;

            bool need = gmk > mk + 11.0f;
            if (__any(need)) {
                float nmk = fmaxf(mk, gmk);
                float f = __builtin_amdgcn_exp2f(mk - nmk);
                mk = nmk;
                sp *= f;
#pragma unroll
                for (int r = 0; r < 4; ++r) {
                    float fr = __shfl(f, (lane & 48) | (quad * 4 + r), 64);
                    c0[r] *= fr; c1[r] *= fr;
                }
            }

            half4_t pf[8];
            float s0 = 0.f, s1 = 0.f, s2 = 0.f, s3 = 0.f;
#pragma unroll
            for (int j = 0; j < 8; ++j) {
                int kt = g * 8 + j;
                float e0 = __builtin_amdgcn_exp2f(a[j][0] * LOG2E - mk);
                float e1 = __builtin_amdgcn_exp2f(a[j][1] * LOG2E - mk);
                float e2 = __builtin_amdgcn_exp2f(a[j][2] * LOG2E - mk);
                float e3 = __builtin_amdgcn_exp2f(a[j][3] * LOG2E - mk);
                e0 = ((keep[0] >> kt) & 1u) ? e0 : 0.0f;
                e1 = ((keep[1] >> kt) & 1u) ? e1 : 0.0f;
                e2 = ((keep[2] >> kt) & 1u) ? e2 : 0.0f;
                e3 = ((keep[3] >> kt) & 1u) ? e3 : 0.0f;
                s0 += e0; s1 += e1; s2 += e2; s3 += e3;
                half4_t t;
                t[0] = (_Float16)e0; t[1] = (_Float16)e1;
                t[2] = (_Float16)e2; t[3] = (_Float16)e3;
                pf[j] = t;
            }
            sp += (s0 + s1) + (s2 + s3);

#pragma unroll
            for (int j = 0; j < 8; ++j) {
                int kt = g * 8 + j;
                int toff = kt * 16 + quad * 4;
                half4_t v0 = *(const half4_t*)(Vlds + l16 * VP        + (toff ^ vx0));
                half4_t v1 = *(const half4_t*)(Vlds + (16 + l16) * VP + (toff ^ vx1));
                c0 = __builtin_amdgcn_mfma_f32_16x16x16f16(pf[j], v0, c0, 0, 0, 0);
                c1 = __builtin_amdgcn_mfma_f32_16x16x16f16(pf[j], v1, c1, 0, 0, 0);
            }
        }

        sp += __shfl_xor(sp, 16, 64);
        sp += __shfl_xor(sp, 32, 64);
        float inv = 1.0f / sp;

#pragma unroll
        for (int r = 0; r < 4; ++r) {
            int s = sb + quad * 4 + r;
            float iv = __shfl(inv, (lane & 48) | (quad * 4 + r), 64);
            float g0 = accg[qt][0][r];
            float g1 = accg[qt][1][r];
            unsigned short* op = ctxg + (size_t)(l * S_NS + s) * D_ + h * C_;
            op[l16]      = (unsigned short)f2b(c0[r] * iv * g0);
            op[16 + l16] = (unsigned short)f2b(c1[r] * iv * g1);
        }
    }
}

// ------------- Output projection (LDS-B): ctxg @ wo^T + bo -> out fp32 (S,L,D) -------------
// Round-5 structure kept: (256,4) + depth-1 prefetch + XCD regroup.
__global__ __launch_bounds__(256, 4) void out_kernel(
    const unsigned short* __restrict__ ctxg,
    const unsigned short* __restrict__ wob,   // bf16 wo
    const float* __restrict__ bo,
    float* __restrict__ out)
{
    __shared__ __align__(16) unsigned short Bl[16384];   // 32 KB

    int tid  = threadIdx.x;
    int lane = tid & 63, wave = tid >> 6;
    int quad = lane >> 4, l16 = lane & 15;

    // --- XCD regroup: invert hw = l%8 + 8*((l/8)*4 + y) ---
    int hw   = blockIdx.y * 192 + blockIdx.x;   // dispatch index (x-fastest)
    int xcd  = hw & 7;
    int slot = hw >> 3;
    int y    = slot & 3;
    int l    = (slot >> 2) * 8 + xcd;

    int n0   = y * 64;
    const unsigned short* W = wob + (size_t)n0 * 256;

#pragma unroll
    for (int j = 0; j < 8; ++j) {
        int c  = j * 256 + tid;
        int n  = c >> 5, kk = c & 31;
        int ks = kk >> 2, kq = kk & 3;
        int sw = (n & 15) ^ kq ^ ((ks & 1) << 2);
        uint4 d = *(const uint4*)(W + n * 256 + kk * 8);
        *(uint4*)&Bl[ks * 2048 + (n >> 4) * 512 + kq * 128 + sw * 8] = d;
    }
    __syncthreads();

    int row0 = l * 256 + wave * 64;
    const unsigned short* arow = ctxg + (size_t)(row0 + l16) * D_ + quad * 8;

    f32x4_t acc[4][4];
#pragma unroll
    for (int mt = 0; mt < 4; ++mt)
#pragma unroll
        for (int nt = 0; nt < 4; ++nt) acc[mt][nt] = (f32x4_t){0.f,0.f,0.f,0.f};

    bf16x8_t a_cur[4], a_nxt[4];
#pragma unroll
    for (int mt = 0; mt < 4; ++mt) a_cur[mt] = *(const bf16x8_t*)(arow + mt * 16 * D_);

    int swb = l16 ^ quad;
#pragma unroll
    for (int ks = 0; ks < 8; ++ks) {
        if (ks < 7) {
#pragma unroll
            for (int mt = 0; mt < 4; ++mt)
                a_nxt[mt] = *(const bf16x8_t*)(arow + mt * 16 * D_ + (ks + 1) * 32);
        }
        int kbase = ks * 2048 + quad * 128 + (swb ^ ((ks & 1) << 2)) * 8;
#pragma unroll
        for (int nt = 0; nt < 4; ++nt) {
            bf16x8_t bfr = *(const bf16x8_t*)&Bl[kbase + nt * 512];
#pragma unroll
            for (int mt = 0; mt < 4; ++mt)
                acc[mt][nt] = __builtin_amdgcn_mfma_f32_16x16x32_bf16(a_cur[mt], bfr, acc[mt][nt], 0, 0, 0);
        }
#pragma unroll
        for (int mt = 0; mt < 4; ++mt) a_cur[mt] = a_nxt[mt];
    }

#pragma unroll
    for (int nt = 0; nt < 4; ++nt) {
        int n = n0 + nt * 16 + l16;
        float bias = bo[n];
#pragma unroll
        for (int mt = 0; mt < 4; ++mt) {
#pragma unroll
            for (int r = 0; r < 4; ++r) {
                int s = wave * 64 + mt * 16 + quad * 4 + r;
                out[((size_t)s * L_NR + l) * D_ + n] = acc[mt][nt][r] + bias;
            }
        }
    }
}

extern "C" void kernel_launch(void* const* d_in, const int* in_sizes, int n_in,
                              void* d_out, int out_size, void* d_ws, size_t ws_size,
                              hipStream_t stream) {
    const float* m     = (const float*)d_in[0];
    const int* seq_pad = (const int*)d_in[1];
    const int* res_pad = (const int*)d_in[2];
    const float* lns   = (const float*)d_in[3];
    const float* lnb   = (const float*)d_in[4];
    const float* wq    = (const float*)d_in[5];
    const float* wk    = (const float*)d_in[6];
    const float* wv    = (const float*)d_in[7];
    const float* wg    = (const float*)d_in[8];
    const float* bg    = (const float*)d_in[9];
    const float* wo    = (const float*)d_in[10];
    const float* bo    = (const float*)d_in[11];
    float* out         = (float*)d_out;

    const size_t NE = (size_t)L_NR * S_NS * D_;   // 12,582,912 elements
    unsigned short* xn   = (unsigned short*)d_ws; // bf16 (L,S,D)
    unsigned short* ctxg = xn + NE;               // bf16 (L,S,D) gated context
    unsigned short* wbf  = ctxg + NE;             // 5 x 65536 bf16 weights

    convw_kernel<<<dim3(64, 5), 256, 0, stream>>>(wq, wk, wv, wg, wo, wbf);
    ln_kernel<<<12288, 256, 0, stream>>>(m, lns, lnb, xn);
    fused_kernel<<<L_NR * H_, 512, 0, stream>>>(xn, wbf, bg, seq_pad, res_pad, ctxg);
    out_kernel<<<dim3(192, 4), 256, 0, stream>>>(ctxg, wbf + 4 * 65536, bo, out);
}

// Round 10
// 196.486 us; speedup vs baseline: 1.4258x; 1.0704x over previous
//
#include <hip/hip_runtime.h>
#include <stdint.h>

#define L_NR 192
#define S_NS 256
#define D_   256
#define H_   8
#define C_   32

typedef __bf16    bf16x8_t __attribute__((ext_vector_type(8)));
typedef _Float16  half4_t  __attribute__((ext_vector_type(4)));
typedef float     f32x4_t  __attribute__((ext_vector_type(4)));

__device__ __forceinline__ float bflo(unsigned int u) { return __uint_as_float(u << 16); }
__device__ __forceinline__ unsigned int f2b(float f) {
    unsigned int x = __float_as_uint(f);
    return (x + 0x7fffu + ((x >> 16) & 1u)) >> 16;   // RNE
}
__device__ __forceinline__ unsigned short f2h(float f) {
    union { _Float16 h; unsigned short u; } cv; cv.h = (_Float16)f; return cv.u;
}

// ---- LayerNorm (blocks 0..12287) + weight bf16 conversion (blocks 12288..12607) ----
// Round-9: merged to save one kernel launch (~10 us of the ~50 us gap budget).
__global__ __launch_bounds__(256) void ln_convw_kernel(
    const float* __restrict__ m,
    const float* __restrict__ lns,
    const float* __restrict__ lnb,
    unsigned short* __restrict__ xn,
    const float* __restrict__ wq, const float* __restrict__ wk,
    const float* __restrict__ wv, const float* __restrict__ wg,
    const float* __restrict__ wo, unsigned short* __restrict__ wbf)
{
    int tid = threadIdx.x;
    int b = blockIdx.x;

    if (b >= 12288) {                       // ---- convw part ----
        int cb  = b - 12288;                // 0..319
        int mat = cb >> 6;                  // 64 blocks per matrix
        int bx  = cb & 63;
        const float* src = (mat == 0) ? wq : (mat == 1) ? wk : (mat == 2) ? wv
                         : (mat == 3) ? wg : wo;
        int i = (bx * 256 + tid) * 4;
        float4 v = *(const float4*)(src + i);
        uint2 w;
        w.x = f2b(v.x) | (f2b(v.y) << 16);
        w.y = f2b(v.z) | (f2b(v.w) << 16);
        *(uint2*)(wbf + (size_t)mat * 65536 + i) = w;
        return;
    }

    // ---- layernorm part: m fp32 (S,L,D) -> xn bf16 (L,S,D) ----
    int lane = tid & 63, wave = tid >> 6;
    int r = b * 4 + wave;                   // r = s*L + l
    int s = r / L_NR, l = r % L_NR;

    float4 x = ((const float4*)(m + (size_t)r * D_))[lane];

    float sum = x.x + x.y + x.z + x.w;
    float ss  = x.x*x.x + x.y*x.y + x.z*x.z + x.w*x.w;
#pragma unroll
    for (int off = 32; off > 0; off >>= 1) {
        sum += __shfl_xor(sum, off, 64);
        ss  += __shfl_xor(ss,  off, 64);
    }
    float mean = sum * (1.0f/256.0f);
    float var  = ss  * (1.0f/256.0f) - mean * mean;
    float rstd = rsqrtf(fmaxf(var, 0.0f) + 1e-5f);

    float4 sc = ((const float4*)lns)[lane];
    float4 bi = ((const float4*)lnb)[lane];

    float y0 = (x.x - mean) * rstd * sc.x + bi.x;
    float y1 = (x.y - mean) * rstd * sc.y + bi.y;
    float y2 = (x.z - mean) * rstd * sc.z + bi.z;
    float y3 = (x.w - mean) * rstd * sc.w + bi.w;

    uint2 w;
    w.x = f2b(y0) | (f2b(y1) << 16);
    w.y = f2b(y2) | (f2b(y3) << 16);
    *(uint2*)(xn + ((size_t)l * S_NS + s) * D_ + lane * 4) = w;
}

// ------------- Fused projections + attention per (l,h) -------------
// Round-8 structure (LDS union, 2 blocks/CU, (512,4), no spills) kept as-is.
#define QP 40    // Q/K LDS row stride (bf16 elems)
#define VP 264   // V^T LDS row stride (f16 elems)
#define VXOR(c) (((((c) >> 3) & 3)) << 4)

__global__ __launch_bounds__(512, 4) void fused_kernel(
    const unsigned short* __restrict__ xn,
    const unsigned short* __restrict__ wbf,   // 4 matrices, bf16, 65536 each
    const float* __restrict__ bg,
    const int* __restrict__ seq_pad, const int* __restrict__ res_pad,
    unsigned short* __restrict__ ctxg)
{
    __shared__ __align__(16) unsigned char SM[65536];   // union: Bst | {Q,K,V}
    __shared__ unsigned int padm[16];

    unsigned short* Bst  = (unsigned short*)SM;               // 65536 B (GEMM phase)
    unsigned short* Qlds = (unsigned short*)SM;               // 20480 B (attn phase)
    unsigned short* Klds = (unsigned short*)(SM + 20480);     // 20480 B
    unsigned short* Vlds = (unsigned short*)(SM + 40960);     // 16896 B (ends 57856)

    int tid  = threadIdx.x;
    int lane = tid & 63, wave = tid >> 6;       // 8 waves
    int quad = lane >> 4, l16 = lane & 15;

    // XCD regroup: the 8 h-blocks of one l are consecutive slots on ONE XCD.
    int hw   = blockIdx.x;
    int xcd  = hw & 7, slot = hw >> 3;
    int h    = slot & 7;
    int l    = (slot >> 3) * 8 + xcd;

    if (tid < 16) {
        unsigned int pm = 0;
        for (int mt = 0; mt < 16; ++mt)
            pm |= (seq_pad[mt * 16 + tid] != 0 ? 1u : 0u) << mt;
        padm[tid] = pm;
    }

    int row0 = l * 256 + wave * 32;
    const unsigned short* arow = xn + (size_t)(row0 + l16) * D_ + quad * 8;

    // early A prefetch for ks=0 (completes during staging)
    bf16x8_t a_cur[2], a_nxt[2];
    a_cur[0] = *(const bf16x8_t*)(arow);
    a_cur[1] = *(const bf16x8_t*)(arow + 16 * D_);

    // stage all 4 B tiles (32 n x 256 k each): coalesced global, swizzled LDS
    const unsigned short* Wh = wbf + (size_t)(h * 32) * 256;
#pragma unroll
    for (int j = 0; j < 8; ++j) {
        int mat = j >> 1;
        int c  = (j & 1) * 512 + tid;
        int n  = c >> 5, kk = c & 31;
        int ks = kk >> 2, kq = kk & 3;
        int sw = (n & 15) ^ kq ^ ((ks & 1) << 2);
        uint4 d = *(const uint4*)(Wh + (size_t)mat * 65536 + n * 256 + kk * 8);
        *(uint4*)&Bst[mat * 8192 + ks * 1024 + (n >> 4) * 512 + kq * 128 + sw * 8] = d;
    }
    __syncthreads();

    f32x4_t acc[4][2][2];
#pragma unroll
    for (int mat = 0; mat < 4; ++mat)
#pragma unroll
        for (int mt = 0; mt < 2; ++mt)
#pragma unroll
            for (int nt = 0; nt < 2; ++nt) acc[mat][mt][nt] = (f32x4_t){0.f,0.f,0.f,0.f};

    int swb = l16 ^ quad;
#pragma unroll
    for (int ks = 0; ks < 8; ++ks) {
        if (ks < 7) {
            a_nxt[0] = *(const bf16x8_t*)(arow + (ks + 1) * 32);
            a_nxt[1] = *(const bf16x8_t*)(arow + 16 * D_ + (ks + 1) * 32);
        }
        int kbase = ks * 1024 + quad * 128 + (swb ^ ((ks & 1) << 2)) * 8;
#pragma unroll
        for (int mat = 0; mat < 4; ++mat) {
#pragma unroll
            for (int nt = 0; nt < 2; ++nt) {
                bf16x8_t bfr = *(const bf16x8_t*)&Bst[mat * 8192 + kbase + nt * 512];
                acc[mat][0][nt] = __builtin_amdgcn_mfma_f32_16x16x32_bf16(a_cur[0], bfr, acc[mat][0][nt], 0, 0, 0);
                acc[mat][1][nt] = __builtin_amdgcn_mfma_f32_16x16x32_bf16(a_cur[1], bfr, acc[mat][1][nt], 0, 0, 0);
            }
        }
        a_cur[0] = a_nxt[0]; a_cur[1] = a_nxt[1];
    }
    __syncthreads();   // ALL waves done reading Bst before Q/K/V overwrite it

    // ---- epilogues: write Q/K/V into the union region + gate regs ----
    const float qscale = 0.17677669529663687f;  // 1/sqrt(32)
    f32x4_t accg[2][2];

#pragma unroll
    for (int mt = 0; mt < 2; ++mt)
#pragma unroll
        for (int nt = 0; nt < 2; ++nt) {
#pragma unroll
            for (int r = 0; r < 4; ++r) {
                int srow = wave * 32 + mt * 16 + quad * 4 + r;
                Qlds[srow * QP + nt * 16 + l16] = (unsigned short)f2b(acc[0][mt][nt][r] * qscale);
                Klds[srow * QP + nt * 16 + l16] = (unsigned short)f2b(acc[1][mt][nt][r]);
            }
            // V: f16, transposed + swizzled, b64 packed
            int cc = nt * 16 + l16;
            int s0 = wave * 32 + mt * 16 + quad * 4;
            half4_t hv;
            hv[0] = (_Float16)acc[2][mt][nt][0];
            hv[1] = (_Float16)acc[2][mt][nt][1];
            hv[2] = (_Float16)acc[2][mt][nt][2];
            hv[3] = (_Float16)acc[2][mt][nt][3];
            *(half4_t*)&Vlds[cc * VP + (s0 ^ VXOR(cc))] = hv;
            // G: sigmoid, round through bf16, keep in regs
            float bgn = bg[h * 32 + nt * 16 + l16];
#pragma unroll
            for (int r = 0; r < 4; ++r)
                accg[mt][nt][r] = bflo(f2b(1.0f / (1.0f + __expf(-(acc[3][mt][nt][r] + bgn)))));
        }
    __syncthreads();   // K/V/Q (cross-wave) complete before attention reads

    // ---------------- attention (2 qt x 16 rows/wave, online softmax) ----
    unsigned int allm = 0xFFFFu;
#pragma unroll
    for (int i = 0; i < 16; ++i) allm &= padm[i];
    int flagall = (res_pad[l] != 0) || (allm == 0xFFFFu);

    unsigned int keep[4];
#pragma unroll
    for (int r = 0; r < 4; ++r)
        keep[r] = flagall ? 0xFFFFu : (~padm[quad * 4 + r] & 0xFFFFu);

    const float LOG2E = 1.4426950408889634f;
    int vx0 = VXOR(l16), vx1 = VXOR(16 + l16);

#pragma unroll
    for (int qt = 0; qt < 2; ++qt) {
        int sb = wave * 32 + qt * 16;

        bf16x8_t qf = *(const bf16x8_t*)(Qlds + (size_t)(sb + l16) * QP + quad * 8);

        float mk = -3.0e38f;
        float sp = 0.0f;
        f32x4_t c0 = (f32x4_t){0.f,0.f,0.f,0.f}, c1 = (f32x4_t){0.f,0.f,0.f,0.f};

#pragma unroll
        for (int g = 0; g < 2; ++g) {
            f32x4_t a[8];
#pragma unroll
            for (int j = 0; j < 8; ++j) {
                int kt = g * 8 + j;
                bf16x8_t kf = *(const bf16x8_t*)(Klds + (kt * 16 + l16) * QP + quad * 8);
                a[j] = __builtin_amdgcn_mfma_f32_16x16x32_bf16(kf, qf, (f32x4_t){0.f,0.f,0.f,0.f}, 0, 0, 0);
            }
            float p0 = fmaxf(fmaxf(a[0][0], a[0][1]), fmaxf(a[0][2], a[0][3]));
            float p1 = fmaxf(fmaxf(a[1][0], a[1][1]), fmaxf(a[1][2], a[1][3]));
            float p2 = fmaxf(fmaxf(a[2][0], a[2][1]), fmaxf(a[2][2], a[2][3]));
            float p3 = fmaxf(fmaxf(a[3][0], a[3][1]), fmaxf(a[3][2], a[3][3]));
            float p4 = fmaxf(fmaxf(a[4][0], a[4][1]), fmaxf(a[4][2], a[4][3]));
            float p5 = fmaxf(fmaxf(a[5][0], a[5][1]), fmaxf(a[5][2], a[5][3]));
            float p6 = fmaxf(fmaxf(a[6][0], a[6][1]), fmaxf(a[6][2], a[6][3]));
            float p7 = fmaxf(fmaxf(a[7][0], a[7][1]), fmaxf(a[7][2], a[7][3]));
            float gm = fmaxf(fmaxf(fmaxf(p0, p1), fmaxf(p2, p3)),
                             fmaxf(fmaxf(p4, p5), fmaxf(p6, p7)));
            gm = fmaxf(gm, __shfl_xor(gm, 16, 64));
            gm = fmaxf(gm, __shfl_xor(gm, 32, 64));
            float gmk = gm * LOG2E;

            bool need = gmk > mk + 11.0f;
            if (__any(need)) {
                float nmk = fmaxf(mk, gmk);
                float f = __builtin_amdgcn_exp2f(mk - nmk);
                mk = nmk;
                sp *= f;
#pragma unroll
                for (int r = 0; r < 4; ++r) {
                    float fr = __shfl(f, (lane & 48) | (quad * 4 + r), 64);
                    c0[r] *= fr; c1[r] *= fr;
                }
            }

            half4_t pf[8];
            float s0 = 0.f, s1 = 0.f, s2 = 0.f, s3 = 0.f;
#pragma unroll
            for (int j = 0; j < 8; ++j) {
                int kt = g * 8 + j;
                float e0 = __builtin_amdgcn_exp2f(a[j][0] * LOG2E - mk);
                float e1 = __builtin_amdgcn_exp2f(a[j][1] * LOG2E - mk);
                float e2 = __builtin_amdgcn_exp2f(a[j][2] * LOG2E - mk);
                float e3 = __builtin_amdgcn_exp2f(a[j][3] * LOG2E - mk);
                e0 = ((keep[0] >> kt) & 1u) ? e0 : 0.0f;
                e1 = ((keep[1] >> kt) & 1u) ? e1 : 0.0f;
                e2 = ((keep[2] >> kt) & 1u) ? e2 : 0.0f;
                e3 = ((keep[3] >> kt) & 1u) ? e3 : 0.0f;
                s0 += e0; s1 += e1; s2 += e2; s3 += e3;
                half4_t t;
                t[0] = (_Float16)e0; t[1] = (_Float16)e1;
                t[2] = (_Float16)e2; t[3] = (_Float16)e3;
                pf[j] = t;
            }
            sp += (s0 + s1) + (s2 + s3);

#pragma unroll
            for (int j = 0; j < 8; ++j) {
                int kt = g * 8 + j;
                int toff = kt * 16 + quad * 4;
                half4_t v0 = *(const half4_t*)(Vlds + l16 * VP        + (toff ^ vx0));
                half4_t v1 = *(const half4_t*)(Vlds + (16 + l16) * VP + (toff ^ vx1));
                c0 = __builtin_amdgcn_mfma_f32_16x16x16f16(pf[j], v0, c0, 0, 0, 0);
                c1 = __builtin_amdgcn_mfma_f32_16x16x16f16(pf[j], v1, c1, 0, 0, 0);
            }
        }

        sp += __shfl_xor(sp, 16, 64);
        sp += __shfl_xor(sp, 32, 64);
        float inv = 1.0f / sp;

#pragma unroll
        for (int r = 0; r < 4; ++r) {
            int s = sb + quad * 4 + r;
            float iv = __shfl(inv, (lane & 48) | (quad * 4 + r), 64);
            float g0 = accg[qt][0][r];
            float g1 = accg[qt][1][r];
            unsigned short* op = ctxg + (size_t)(l * S_NS + s) * D_ + h * C_;
            op[l16]      = (unsigned short)f2b(c0[r] * iv * g0);
            op[16 + l16] = (unsigned short)f2b(c1[r] * iv * g1);
        }
    }
}

// ------------- Output projection (LDS-B): ctxg @ wo^T + bo -> out fp32 (S,L,D) -------------
// Round-9: coalesced epilogue. The old epilogue issued 64 SCALAR stores/thread
// in 64B segments scattered 196KB apart -> WRITE_SIZE 76.7MB for a 48MB output
// (1.6x partial-line amplification). Now: reuse the dead B-tile LDS as a
// padded fp32 transpose tile [128][68] (34KB union, still 4 blocks/CU), two
// halves; stream float4 stores, 256B contiguous per s-row. Bias added at the
// same f32 point -> bit-identical. Write bank pattern 2-way (free); read b128
// distribution-exact (conflict-free).
__global__ __launch_bounds__(256, 4) void out_kernel(
    const unsigned short* __restrict__ ctxg,
    const unsigned short* __restrict__ wob,   // bf16 wo
    const float* __restrict__ bo,
    float* __restrict__ out)
{
    __shared__ __align__(16) unsigned char OSM[34816];   // union: B (32KB) | T [128][68] f32
    unsigned short* Bl = (unsigned short*)OSM;
    float*          T  = (float*)OSM;

    int tid  = threadIdx.x;
    int lane = tid & 63, wave = tid >> 6;
    int quad = lane >> 4, l16 = lane & 15;

    // --- XCD regroup: invert hw = l%8 + 8*((l/8)*4 + y) ---
    int hw   = blockIdx.y * 192 + blockIdx.x;   // dispatch index (x-fastest)
    int xcd  = hw & 7;
    int slot = hw >> 3;
    int y    = slot & 3;
    int l    = (slot >> 2) * 8 + xcd;

    int n0   = y * 64;
    const unsigned short* W = wob + (size_t)n0 * 256;

#pragma unroll
    for (int j = 0; j < 8; ++j) {
        int c  = j * 256 + tid;
        int n  = c >> 5, kk = c & 31;
        int ks = kk >> 2, kq = kk & 3;
        int sw = (n & 15) ^ kq ^ ((ks & 1) << 2);
        uint4 d = *(const uint4*)(W + n * 256 + kk * 8);
        *(uint4*)&Bl[ks * 2048 + (n >> 4) * 512 + kq * 128 + sw * 8] = d;
    }
    __syncthreads();

    int row0 = l * 256 + wave * 64;
    const unsigned short* arow = ctxg + (size_t)(row0 + l16) * D_ + quad * 8;

    f32x4_t acc[4][4];
#pragma unroll
    for (int mt = 0; mt < 4; ++mt)
#pragma unroll
        for (int nt = 0; nt < 4; ++nt) acc[mt][nt] = (f32x4_t){0.f,0.f,0.f,0.f};

    bf16x8_t a_cur[4], a_nxt[4];
#pragma unroll
    for (int mt = 0; mt < 4; ++mt) a_cur[mt] = *(const bf16x8_t*)(arow + mt * 16 * D_);

    int swb = l16 ^ quad;
#pragma unroll
    for (int ks = 0; ks < 8; ++ks) {
        if (ks < 7) {
#pragma unroll
            for (int mt = 0; mt < 4; ++mt)
                a_nxt[mt] = *(const bf16x8_t*)(arow + mt * 16 * D_ + (ks + 1) * 32);
        }
        int kbase = ks * 2048 + quad * 128 + (swb ^ ((ks & 1) << 2)) * 8;
#pragma unroll
        for (int nt = 0; nt < 4; ++nt) {
            bf16x8_t bfr = *(const bf16x8_t*)&Bl[kbase + nt * 512];
#pragma unroll
            for (int mt = 0; mt < 4; ++mt)
                acc[mt][nt] = __builtin_amdgcn_mfma_f32_16x16x32_bf16(a_cur[mt], bfr, acc[mt][nt], 0, 0, 0);
        }
#pragma unroll
        for (int mt = 0; mt < 4; ++mt) a_cur[mt] = a_nxt[mt];
    }
    __syncthreads();   // all waves done reading Bl before T overwrites it

    // bias for this thread's fixed n-slot (c4 = tid & 15)
    float4 b4 = ((const float4*)(bo + n0))[tid & 15];

#pragma unroll
    for (int half = 0; half < 2; ++half) {
        if ((wave >> 1) == half) {
            int sl0 = (wave & 1) * 64;
#pragma unroll
            for (int mt = 0; mt < 4; ++mt)
#pragma unroll
                for (int nt = 0; nt < 4; ++nt)
#pragma unroll
                    for (int r = 0; r < 4; ++r) {
                        int sl = sl0 + mt * 16 + quad * 4 + r;
                        T[sl * 68 + nt * 16 + l16] = acc[mt][nt][r];
                    }
        }
        __syncthreads();
#pragma unroll
        for (int i = 0; i < 8; ++i) {
            int idx = i * 256 + tid;
            int sl = idx >> 4, c4 = idx & 15;
            float4 v = *(float4*)&T[sl * 68 + c4 * 4];
            v.x += b4.x; v.y += b4.y; v.z += b4.z; v.w += b4.w;
            *(float4*)&out[((size_t)(half * 128 + sl) * L_NR + l) * D_ + n0 + c4 * 4] = v;
        }
        if (half == 0) __syncthreads();   // T dead before half-1 overwrite
    }
}

extern "C" void kernel_launch(void* const* d_in, const int* in_sizes, int n_in,
                              void* d_out, int out_size, void* d_ws, size_t ws_size,
                              hipStream_t stream) {
    const float* m     = (const float*)d_in[0];
    const int* seq_pad = (const int*)d_in[1];
    const int* res_pad = (const int*)d_in[2];
    const float* lns   = (const float*)d_in[3];
    const float* lnb   = (const float*)d_in[4];
    const float* wq    = (const float*)d_in[5];
    const float* wk    = (const float*)d_in[6];
    const float* wv    = (const float*)d_in[7];
    const float* wg    = (const float*)d_in[8];
    const float* bg    = (const float*)d_in[9];
    const float* wo    = (const float*)d_in[10];
    const float* bo    = (const float*)d_in[11];
    float* out         = (float*)d_out;

    const size_t NE = (size_t)L_NR * S_NS * D_;   // 12,582,912 elements
    unsigned short* xn   = (unsigned short*)d_ws; // bf16 (L,S,D)
    unsigned short* ctxg = xn + NE;               // bf16 (L,S,D) gated context
    unsigned short* wbf  = ctxg + NE;             // 5 x 65536 bf16 weights

    ln_convw_kernel<<<12288 + 320, 256, 0, stream>>>(m, lns, lnb, xn,
                                                     wq, wk, wv, wg, wo, wbf);
    fused_kernel<<<L_NR * H_, 512, 0, stream>>>(xn, wbf, bg, seq_pad, res_pad, ctxg);
    out_kernel<<<dim3(192, 4), 256, 0, stream>>>(ctxg, wbf + 4 * 65536, bo, out);
}